// Round 1
// baseline (14606.197 us; speedup 1.0000x reference)
//
#include <hip/hip_runtime.h>
#include <math.h>

// Problem constants
constexpr int Bn = 2048, Mm = 2, Vv = 25, Dd = 64;
constexpr int C1 = 128, C2 = 256, Kk = 3, Uu = 256;
constexpr int NJ = Mm*Vv*Uu;     // 12800
constexpr int NBd = Mm*Uu;       // 512
constexpr int SD = NJ+NBd+Uu;    // 13568
constexpr int Nn = Bn*Mm;        // 4096
constexpr int N3 = Nn*Vv;        // 102400

__device__ __forceinline__ float hsig(float z){ return fminf(fmaxf(0.2f*z+0.5f,0.f),1.f); }

// ---------------------------------------------------------------------------
// Kernel A: per-n fused  y0 = xg@wg0+bg0 ; y = relu(einsum(y0, ei0*A))
// block = one n (4096 blocks, 256 thr). Partition: tx in [0,64) owns cols,
// wy = wave id owns a v-group {7,6,6,6}.  wg0 staged in 16-row LDS chunks so
// it is read from L2 exactly once per block.
// ---------------------------------------------------------------------------
__global__ __launch_bounds__(256,2) void kA(
    const float* __restrict__ x, const float* __restrict__ wg0, const float* __restrict__ bg0,
    const float* __restrict__ A, const float* __restrict__ ei, float* __restrict__ y_out)
{
  __shared__ float xs[Vv*Dd];        // 1600
  __shared__ float wchunk[16*384];   // 6144
  __shared__ float y0s[Vv*384];      // 9600
  __shared__ float a0s[Kk*Vv*Vv];    // 1875
  const int n = blockIdx.x, t = threadIdx.x;
  const int tx = t & 63, wy = t >> 6;
  const int vstart = (wy==0)?0:(1+6*wy);
  const int vcnt   = (wy==0)?7:6;
  const float* xrow = x + (size_t)n*1600;
  for(int i=t;i<1600;i+=256) xs[i]=xrow[i];
  for(int i=t;i<1875;i+=256) a0s[i]=ei[i]*A[i];

  float acc[7][6];
  #pragma unroll
  for(int vi=0;vi<7;++vi)
    #pragma unroll
    for(int c=0;c<6;++c) acc[vi][c] = bg0[tx + 64*c];

  for(int d0=0; d0<64; d0+=16){
    __syncthreads();
    for(int i=t;i<1536;i+=256){                 // 16*384 floats as float4
      int dd=i/96, c4=(i%96)*4;
      *(float4*)&wchunk[dd*384+c4] = *(const float4*)&wg0[(size_t)(d0+dd)*384+c4];
    }
    __syncthreads();
    for(int dd=0;dd<16;++dd){
      float wv[6];
      #pragma unroll
      for(int c=0;c<6;++c) wv[c]=wchunk[dd*384 + tx + 64*c];  // stride-64: conflict-free
      #pragma unroll
      for(int vi=0;vi<7;++vi){
        if(vi<vcnt){
          float xv = xs[(vstart+vi)*64 + d0+dd];               // broadcast
          #pragma unroll
          for(int c=0;c<6;++c) acc[vi][c] += xv*wv[c];
        }
      }
    }
  }
  #pragma unroll
  for(int vi=0;vi<7;++vi){
    if(vi<vcnt){
      #pragma unroll
      for(int c=0;c<6;++c) y0s[(vstart+vi)*384 + tx + 64*c] = acc[vi][c];
    }
  }
  __syncthreads();
  // einsum: y[w][cc] = sum_{k,v} y0[v][k*128+cc] * a0[k][v][w]; tx owns 2 cols, wy owns w-group
  float ya[7][2];
  #pragma unroll
  for(int vi=0;vi<7;++vi){ ya[vi][0]=0.f; ya[vi][1]=0.f; }
  for(int k=0;k<3;++k){
    for(int v=0;v<25;++v){
      float t0 = y0s[v*384 + k*128 + tx*2];
      float t1 = y0s[v*384 + k*128 + tx*2+1];
      #pragma unroll
      for(int vi=0;vi<7;++vi){
        if(vi<vcnt){
          float av = a0s[k*625 + v*25 + (vstart+vi)];
          ya[vi][0] += t0*av; ya[vi][1] += t1*av;
        }
      }
    }
  }
  float* yrow = y_out + (size_t)n*3200;
  #pragma unroll
  for(int vi=0;vi<7;++vi){
    if(vi<vcnt){
      int w = vstart+vi;
      yrow[w*128 + tx*2]   = fmaxf(ya[vi][0],0.f);
      yrow[w*128 + tx*2+1] = fmaxf(ya[vi][1],0.f);
    }
  }
}

// ---------------------------------------------------------------------------
// Kernel B: per-n fused  res = y@wr1+br1 ; z0_k = y@wg1_k+bg1_k ;
//           feat = relu(einsum(z0, ei1*A) + res)
// Same partition as kA; tx owns 4 consecutive cols (float4 LDS ops).
// ---------------------------------------------------------------------------
__global__ __launch_bounds__(256,2) void kB(
    const float* __restrict__ y_in, const float* __restrict__ wg1, const float* __restrict__ bg1,
    const float* __restrict__ wr1, const float* __restrict__ br1,
    const float* __restrict__ A, const float* __restrict__ ei, float* __restrict__ feat)
{
  __shared__ float ys[Vv*C1];       // 3200
  __shared__ float wchunk[32*256];  // 8192
  __shared__ float tmp[Vv*C2];      // 6400
  __shared__ float a1s[Kk*Vv*Vv];   // 1875
  const int n = blockIdx.x, t = threadIdx.x;
  const int tx = t & 63, wy = t >> 6;
  const int vstart = (wy==0)?0:(1+6*wy);
  const int vcnt   = (wy==0)?7:6;
  const float* yrow = y_in + (size_t)n*3200;
  for(int i=t;i<3200;i+=256) ys[i]=yrow[i];
  for(int i=t;i<1875;i+=256) a1s[i]=ei[1875+i]*A[i];

  float acc[7][4];
  #pragma unroll
  for(int vi=0;vi<7;++vi)
    #pragma unroll
    for(int c=0;c<4;++c) acc[vi][c] = br1[tx*4+c];

  // res = y @ wr1
  for(int d0=0; d0<128; d0+=32){
    __syncthreads();
    for(int i=t;i<2048;i+=256){
      int dd=i>>6, c4=(i&63)<<2;
      *(float4*)&wchunk[dd*256+c4] = *(const float4*)&wr1[(size_t)(d0+dd)*256+c4];
    }
    __syncthreads();
    for(int dd=0;dd<32;++dd){
      float4 wv = *(const float4*)&wchunk[dd*256 + tx*4];
      #pragma unroll
      for(int vi=0;vi<7;++vi){
        if(vi<vcnt){
          float yv = ys[(vstart+vi)*128 + d0+dd];
          acc[vi][0]+=yv*wv.x; acc[vi][1]+=yv*wv.y; acc[vi][2]+=yv*wv.z; acc[vi][3]+=yv*wv.w;
        }
      }
    }
  }
  // z0 per k-plane + einsum accumulate
  for(int k=0;k<3;++k){
    float za[7][4];
    #pragma unroll
    for(int vi=0;vi<7;++vi)
      #pragma unroll
      for(int c=0;c<4;++c) za[vi][c] = bg1[k*256 + tx*4+c];
    for(int d0=0; d0<128; d0+=32){
      __syncthreads();
      for(int i=t;i<2048;i+=256){
        int dd=i>>6, c4=(i&63)<<2;
        *(float4*)&wchunk[dd*256+c4] = *(const float4*)&wg1[(size_t)(d0+dd)*768 + k*256 + c4];
      }
      __syncthreads();
      for(int dd=0;dd<32;++dd){
        float4 wv = *(const float4*)&wchunk[dd*256 + tx*4];
        #pragma unroll
        for(int vi=0;vi<7;++vi){
          if(vi<vcnt){
            float yv = ys[(vstart+vi)*128 + d0+dd];
            za[vi][0]+=yv*wv.x; za[vi][1]+=yv*wv.y; za[vi][2]+=yv*wv.z; za[vi][3]+=yv*wv.w;
          }
        }
      }
    }
    #pragma unroll
    for(int vi=0;vi<7;++vi){
      if(vi<vcnt)
        *(float4*)&tmp[(vstart+vi)*256 + tx*4] = make_float4(za[vi][0],za[vi][1],za[vi][2],za[vi][3]);
    }
    __syncthreads();
    for(int v=0; v<25; ++v){
      float4 t4 = *(const float4*)&tmp[v*256 + tx*4];
      #pragma unroll
      for(int vi=0;vi<7;++vi){
        if(vi<vcnt){
          float av = a1s[k*625 + v*25 + (vstart+vi)];
          acc[vi][0]+=t4.x*av; acc[vi][1]+=t4.y*av; acc[vi][2]+=t4.z*av; acc[vi][3]+=t4.w*av;
        }
      }
    }
  }
  float* frow = feat + (size_t)n*6400;
  #pragma unroll
  for(int vi=0;vi<7;++vi){
    if(vi<vcnt){
      int w = vstart+vi;
      *(float4*)&frow[w*256 + tx*4] = make_float4(
          fmaxf(acc[vi][0],0.f), fmaxf(acc[vi][1],0.f),
          fmaxf(acc[vi][2],0.f), fmaxf(acc[vi][3],0.f));
    }
  }
}

// ---------------------------------------------------------------------------
// Fused GEMM + LSTM pointwise.  z = [feat_row | h_row] @ [Wm ; Wr] + bias,
// gates (i,f,g,o) = cols (g*256+u).  Tile: BR rows x 64 u (=256 gate cols).
// MODE 0: joint (rows=102400, KF=256)  1: body (4096, 6400)  2: whole (2048, 12800)
// ---------------------------------------------------------------------------
template<int MODE>
__device__ __forceinline__ void rowmap(int row, int& hoff, int& boff){
  if(MODE==0){ int b=row/50; int j=row-b*50; hoff=b*SD + j*256; boff=j*1024; }
  else if(MODE==1){ int b=row>>1; int m=row&1; hoff=b*SD + NJ + m*256; boff=m*1024; }
  else { hoff=row*SD + NJ + NBd; boff=0; }
}

template<int MODE, int RPT>
__global__ __launch_bounds__(256,2) void kLSTM(
    const float* __restrict__ feat, const float* __restrict__ h0, const float* __restrict__ c0,
    const float* __restrict__ Wm, const float* __restrict__ Wr,
    const float* __restrict__ bias, float* __restrict__ out)
{
  constexpr int BR = RPT*16;
  constexpr int KF = (MODE==0)?256:(MODE==1)?6400:12800;
  constexpr int KT = KF+256;
  __shared__ float As[BR*33];       // pad 33: conflict-free a-reads
  __shared__ float Bs[32*256];
  const int t = threadIdx.x;
  const int tx = t & 15, ty = t >> 4;
  const int r0 = blockIdx.x*BR;
  const int u0 = blockIdx.y*64;
  float acc[RPT][16];
  #pragma unroll
  for(int i=0;i<RPT;++i)
    #pragma unroll
    for(int j=0;j<16;++j) acc[i][j]=0.f;

  for(int k0=0;k0<KT;k0+=32){
    const bool isF = (k0<KF);
    #pragma unroll
    for(int i=0;i<BR/32;++i){                    // A tile: BR x 32
      int fidx = t + i*256;
      int row = fidx>>3, k4=(fidx&7)<<2;
      int rg = r0+row;
      const float* src;
      if(isF) src = feat + (size_t)rg*KF + (k0+k4);
      else { int hoff,boff; rowmap<MODE>(rg,hoff,boff); (void)boff; src = h0 + (size_t)hoff + (k0-KF+k4); }
      float4 v4 = *(const float4*)src;
      float* dst=&As[row*33+k4];
      dst[0]=v4.x; dst[1]=v4.y; dst[2]=v4.z; dst[3]=v4.w;
    }
    #pragma unroll
    for(int i=0;i<8;++i){                        // B tile: 32 x 256 gate cols
      int fidx=t+i*256;
      int kk=fidx>>6, j4=(fidx&63)<<2;
      int wcol=(j4>>6)*256 + u0 + (j4&63);
      const float* wsrc = isF ? (Wm + (size_t)(k0+kk)*1024 + wcol)
                              : (Wr + (size_t)(k0-KF+kk)*1024 + wcol);
      *(float4*)&Bs[kk*256+j4] = *(const float4*)wsrc;
    }
    __syncthreads();
    #pragma unroll
    for(int kk=0;kk<32;++kk){
      float a[RPT];
      #pragma unroll
      for(int ri=0;ri<RPT;++ri) a[ri]=As[(ty*RPT+ri)*33+kk];
      #pragma unroll
      for(int g=0;g<4;++g){
        float4 bv = *(const float4*)&Bs[kk*256 + g*64 + tx*4];
        #pragma unroll
        for(int ri=0;ri<RPT;++ri){
          acc[ri][g*4+0]+=a[ri]*bv.x;
          acc[ri][g*4+1]+=a[ri]*bv.y;
          acc[ri][g*4+2]+=a[ri]*bv.z;
          acc[ri][g*4+3]+=a[ri]*bv.w;
        }
      }
    }
    __syncthreads();
  }
  #pragma unroll
  for(int ri=0;ri<RPT;++ri){
    int rg = r0 + ty*RPT + ri;
    int hoff,boff; rowmap<MODE>(rg,hoff,boff);
    #pragma unroll
    for(int ui=0;ui<4;++ui){
      int u = u0 + tx*4 + ui;
      float zi = acc[ri][0+ui]  + bias[boff + u];
      float zf = acc[ri][4+ui]  + bias[boff + 256 + u];
      float zg = acc[ri][8+ui]  + bias[boff + 512 + u];
      float zo = acc[ri][12+ui] + bias[boff + 768 + u];
      float iv=hsig(zi), fv=hsig(zf), gv=tanhf(zg), ov=hsig(zo);
      float cc = c0[(size_t)hoff+u];
      float c2 = fv*cc + iv*gv;
      out[(size_t)hoff+u] = ov*tanhf(c2);
    }
  }
}

extern "C" void kernel_launch(void* const* d_in, const int* in_sizes, int n_in,
                              void* d_out, int out_size, void* d_ws, size_t ws_size,
                              hipStream_t stream)
{
  const float* x   = (const float*)d_in[0];
  const float* h0  = (const float*)d_in[1];
  const float* c0  = (const float*)d_in[2];
  const float* A   = (const float*)d_in[3];
  const float* ei  = (const float*)d_in[4];
  const float* wg0 = (const float*)d_in[5];
  const float* bg0 = (const float*)d_in[6];
  const float* wg1 = (const float*)d_in[7];
  const float* bg1 = (const float*)d_in[8];
  const float* wr1 = (const float*)d_in[9];
  const float* br1 = (const float*)d_in[10];
  const float* kern  = (const float*)d_in[11];
  const float* kernB = (const float*)d_in[12];
  const float* kernW = (const float*)d_in[13];
  const float* rk    = (const float*)d_in[14];
  const float* rkB   = (const float*)d_in[15];
  const float* rkW   = (const float*)d_in[16];
  const float* bias  = (const float*)d_in[17];
  const float* biasB = (const float*)d_in[18];
  const float* biasW = (const float*)d_in[19];
  float* out = (float*)d_out;
  float* ws  = (float*)d_ws;
  float* y_ws  = ws;                          // 4096*3200 = 13.1M floats
  float* featw = ws + (size_t)Nn*3200;        // 4096*6400 = 26.2M floats (total 157 MB)

  kA<<<Nn,256,0,stream>>>(x,wg0,bg0,A,ei,y_ws);
  kB<<<Nn,256,0,stream>>>(y_ws,wg1,bg1,wr1,br1,A,ei,featw);
  kLSTM<0,4><<<dim3(N3/64,4),256,0,stream>>>(featw,h0,c0,kern,rk,bias,out);   // 6400 blocks
  kLSTM<1,2><<<dim3(Nn/32,4),256,0,stream>>>(featw,h0,c0,kernB,rkB,biasB,out);// 512 blocks
  kLSTM<2,2><<<dim3(Bn/32,4),256,0,stream>>>(featw,h0,c0,kernW,rkW,biasW,out);// 256 blocks
}

// Round 2
// 6744.395 us; speedup vs baseline: 2.1657x; 2.1657x over previous
//
#include <hip/hip_runtime.h>
#include <math.h>

// Problem constants
constexpr int Bn = 2048, Mm = 2, Vv = 25, Dd = 64;
constexpr int C1 = 128, C2 = 256, Kk = 3, Uu = 256;
constexpr int NJ = Mm*Vv*Uu;     // 12800
constexpr int NBd = Mm*Uu;       // 512
constexpr int SD = NJ+NBd+Uu;    // 13568
constexpr int Nn = Bn*Mm;        // 4096
constexpr int N3 = Nn*Vv;        // 102400
constexpr int NCH = 4;           // n-chunks (keeps ws at 157.3 MB)
constexpr int NnC = Nn/NCH;      // 1024 n per chunk
constexpr int RC  = NnC*Vv;      // 25600 rows per chunk

__device__ __forceinline__ float hsig(float z){ return fminf(fmaxf(0.2f*z+0.5f,0.f),1.f); }

// ---------------------------------------------------------------------------
// kMix<SW>: v-mixing by adjacency, applied BEFORE the channel GEMM (commutes).
// dst[(n*25+w)*(3*SW) + k*SW+d] = sum_v (ei[eoff..]*A)[k,v,w] * src[(n*25+v)*SW + d]
// block = one n, blockDim = 3*SW (each thread owns one (k,d) column).
// ---------------------------------------------------------------------------
template<int SW>
__global__ __launch_bounds__(SW*3) void kMix(
    const float* __restrict__ src, const float* __restrict__ Amat,
    const float* __restrict__ ei, int eoff, float* __restrict__ dst)
{
  __shared__ float xs[Vv*SW];
  __shared__ float as[Kk*Vv*Vv];
  const int n = blockIdx.x, t = threadIdx.x;
  const float* srow = src + (size_t)n*(Vv*SW);
  for(int i=t;i<Vv*SW;i+=SW*3) xs[i]=srow[i];
  for(int i=t;i<Kk*Vv*Vv;i+=SW*3) as[i]=ei[eoff+i]*Amat[i];
  __syncthreads();
  const int k = t/SW, d = t%SW;
  float acc[Vv];
  #pragma unroll
  for(int w=0;w<Vv;++w) acc[w]=0.f;
  for(int v=0;v<Vv;++v){
    float xv = xs[v*SW+d];                 // lanes: d consecutive -> conflict-free
    const float* ap = &as[k*625 + v*25];   // wave-uniform -> broadcast
    #pragma unroll
    for(int w=0;w<Vv;++w) acc[w] += ap[w]*xv;
  }
  float* drow = dst + (size_t)n*(Vv*3*SW);
  for(int w=0;w<Vv;++w) drow[w*(3*SW) + t] = acc[w];
}

// ---------------------------------------------------------------------------
// kGemm<MODE>: tiled fp32 GEMM + fused bias/relu epilogue.
// MODE 1: y(RCx128)    = relu( xcat(RCx192) @ Wg0cat + bias0(w,c) )
// MODE 2: feat(RCx256) = relu( [ycat(RCx384)|y(RCx128)] @ [wg1;wr1] + bias1(w,c) )
// bias(w,c) = (MODE2? br1[c]:0) + sum_k asum[k][w]*bg[k*NC+c],
//   asum[k][w] = sum_v (ei*A)[k,v,w].
// Tile 64x128, 256 thr, 4x8 micro (acc=32 regs — no spill). K-step 32.
// ---------------------------------------------------------------------------
template<int MODE>
__global__ __launch_bounds__(256,2) void kGemm(
    const float* __restrict__ A1, const float* __restrict__ A2,
    const float* __restrict__ W1, const float* __restrict__ W2,
    const float* __restrict__ bg, const float* __restrict__ br,
    const float* __restrict__ Amat, const float* __restrict__ ei,
    float* __restrict__ out)
{
  constexpr int KT = (MODE==1)?192:512;
  constexpr int NT = (MODE==1)?128:256;
  constexpr int EOFF = (MODE==1)?0:1875;
  __shared__ float As[64*33];
  __shared__ float Bs[32*128];
  __shared__ float asums[75];
  const int t = threadIdx.x;
  const int r0 = blockIdx.x*64, c0 = blockIdx.y*128;
  if(t<75){
    int k=t/25, w=t%25; float s=0.f;
    for(int v=0;v<25;++v) s += ei[EOFF + k*625+v*25+w]*Amat[k*625+v*25+w];
    asums[t]=s;
  }
  const int tx = t&15, ty = t>>4;
  float acc[4][8];
  #pragma unroll
  for(int i=0;i<4;++i)
    #pragma unroll
    for(int j=0;j<8;++j) acc[i][j]=0.f;

  for(int k0=0;k0<KT;k0+=32){
    __syncthreads();
    { // stage A: 64 rows x 32 k  (2048 floats, 8/thread)
      int row = t>>2, kb = (t&3)*8;
      const float* src;
      if constexpr (MODE==1) src = A1 + (size_t)(r0+row)*192 + (k0+kb);
      else src = (k0<384) ? (A1 + (size_t)(r0+row)*384 + (k0+kb))
                          : (A2 + (size_t)(r0+row)*128 + (k0-384+kb));
      float4 v0 = *(const float4*)src;
      float4 v1 = *(const float4*)(src+4);
      float* dA = &As[row*33+kb];
      dA[0]=v0.x; dA[1]=v0.y; dA[2]=v0.z; dA[3]=v0.w;
      dA[4]=v1.x; dA[5]=v1.y; dA[6]=v1.z; dA[7]=v1.w;
    }
    #pragma unroll
    for(int i=0;i<4;++i){ // stage B: 32 k x 128 cols (4096 floats, 16/thread)
      int f = i*1024 + t*4;
      int kk = f>>7, c4 = f&127;
      int kg = k0+kk;
      const float* wsrc;
      if constexpr (MODE==1){
        int pl = kg>>6, d = kg&63;
        wsrc = W1 + (size_t)d*384 + pl*128 + c4;
      } else {
        if(kg<384){ int pl = kg>>7, d = kg&127; wsrc = W1 + (size_t)d*768 + pl*256 + c0 + c4; }
        else      { wsrc = W2 + (size_t)(kg-384)*256 + c0 + c4; }
      }
      *(float4*)&Bs[kk*128+c4] = *(const float4*)wsrc;
    }
    __syncthreads();
    #pragma unroll
    for(int kk=0;kk<32;++kk){
      float4 b0 = *(const float4*)&Bs[kk*128 + tx*4];        // 2-way alias: free
      float4 b1 = *(const float4*)&Bs[kk*128 + 64 + tx*4];
      #pragma unroll
      for(int ri=0;ri<4;++ri){
        float av = As[(ty*4+ri)*33+kk];                      // pad-33: conflict-free
        acc[ri][0]+=av*b0.x; acc[ri][1]+=av*b0.y; acc[ri][2]+=av*b0.z; acc[ri][3]+=av*b0.w;
        acc[ri][4]+=av*b1.x; acc[ri][5]+=av*b1.y; acc[ri][6]+=av*b1.z; acc[ri][7]+=av*b1.w;
      }
    }
  }
  #pragma unroll
  for(int ri=0;ri<4;++ri){
    int rg = r0 + ty*4 + ri;
    int w = rg % 25;
    float a0w = asums[w], a1w = asums[25+w], a2w = asums[50+w];
    #pragma unroll
    for(int half=0; half<2; ++half){
      float4 o;
      float* op = &o.x;
      #pragma unroll
      for(int ci=0;ci<4;++ci){
        int cg = c0 + half*64 + tx*4 + ci;
        float b;
        if constexpr (MODE==1) b = a0w*bg[cg] + a1w*bg[128+cg] + a2w*bg[256+cg];
        else                   b = br[cg] + a0w*bg[cg] + a1w*bg[256+cg] + a2w*bg[512+cg];
        op[ci] = fmaxf(acc[ri][half*4+ci] + b, 0.f);
      }
      *(float4*)&out[(size_t)rg*NT + c0 + half*64 + tx*4] = o;
    }
  }
}

// ---------------------------------------------------------------------------
// Fused GEMM + LSTM pointwise (unchanged from round 0 — verified correct).
// ---------------------------------------------------------------------------
template<int MODE>
__device__ __forceinline__ void rowmap(int row, int& hoff, int& boff){
  if(MODE==0){ int b=row/50; int j=row-b*50; hoff=b*SD + j*256; boff=j*1024; }
  else if(MODE==1){ int b=row>>1; int m=row&1; hoff=b*SD + NJ + m*256; boff=m*1024; }
  else { hoff=row*SD + NJ + NBd; boff=0; }
}

template<int MODE, int RPT>
__global__ __launch_bounds__(256,2) void kLSTM(
    const float* __restrict__ feat, const float* __restrict__ h0, const float* __restrict__ c0,
    const float* __restrict__ Wm, const float* __restrict__ Wr,
    const float* __restrict__ bias, float* __restrict__ out)
{
  constexpr int BR = RPT*16;
  constexpr int KF = (MODE==0)?256:(MODE==1)?6400:12800;
  constexpr int KT = KF+256;
  __shared__ float As[BR*33];
  __shared__ float Bs[32*256];
  const int t = threadIdx.x;
  const int tx = t & 15, ty = t >> 4;
  const int r0 = blockIdx.x*BR;
  const int u0 = blockIdx.y*64;
  float acc[RPT][16];
  #pragma unroll
  for(int i=0;i<RPT;++i)
    #pragma unroll
    for(int j=0;j<16;++j) acc[i][j]=0.f;

  for(int k0=0;k0<KT;k0+=32){
    const bool isF = (k0<KF);
    #pragma unroll
    for(int i=0;i<BR/32;++i){
      int fidx = t + i*256;
      int row = fidx>>3, k4=(fidx&7)<<2;
      int rg = r0+row;
      const float* src;
      if(isF) src = feat + (size_t)rg*KF + (k0+k4);
      else { int hoff,boff; rowmap<MODE>(rg,hoff,boff); (void)boff; src = h0 + (size_t)hoff + (k0-KF+k4); }
      float4 v4 = *(const float4*)src;
      float* dst=&As[row*33+k4];
      dst[0]=v4.x; dst[1]=v4.y; dst[2]=v4.z; dst[3]=v4.w;
    }
    #pragma unroll
    for(int i=0;i<8;++i){
      int fidx=t+i*256;
      int kk=fidx>>6, j4=(fidx&63)<<2;
      int wcol=(j4>>6)*256 + u0 + (j4&63);
      const float* wsrc = isF ? (Wm + (size_t)(k0+kk)*1024 + wcol)
                              : (Wr + (size_t)(k0-KF+kk)*1024 + wcol);
      *(float4*)&Bs[kk*256+j4] = *(const float4*)wsrc;
    }
    __syncthreads();
    #pragma unroll
    for(int kk=0;kk<32;++kk){
      float a[RPT];
      #pragma unroll
      for(int ri=0;ri<RPT;++ri) a[ri]=As[(ty*RPT+ri)*33+kk];
      #pragma unroll
      for(int g=0;g<4;++g){
        float4 bv = *(const float4*)&Bs[kk*256 + g*64 + tx*4];
        #pragma unroll
        for(int ri=0;ri<RPT;++ri){
          acc[ri][g*4+0]+=a[ri]*bv.x;
          acc[ri][g*4+1]+=a[ri]*bv.y;
          acc[ri][g*4+2]+=a[ri]*bv.z;
          acc[ri][g*4+3]+=a[ri]*bv.w;
        }
      }
    }
    __syncthreads();
  }
  #pragma unroll
  for(int ri=0;ri<RPT;++ri){
    int rg = r0 + ty*RPT + ri;
    int hoff,boff; rowmap<MODE>(rg,hoff,boff);
    #pragma unroll
    for(int ui=0;ui<4;++ui){
      int u = u0 + tx*4 + ui;
      float zi = acc[ri][0+ui]  + bias[boff + u];
      float zf = acc[ri][4+ui]  + bias[boff + 256 + u];
      float zg = acc[ri][8+ui]  + bias[boff + 512 + u];
      float zo = acc[ri][12+ui] + bias[boff + 768 + u];
      float iv=hsig(zi), fv=hsig(zf), gv=tanhf(zg), ov=hsig(zo);
      float cc = c0[(size_t)hoff+u];
      float c2 = fv*cc + iv*gv;
      out[(size_t)hoff+u] = ov*tanhf(c2);
    }
  }
}

extern "C" void kernel_launch(void* const* d_in, const int* in_sizes, int n_in,
                              void* d_out, int out_size, void* d_ws, size_t ws_size,
                              hipStream_t stream)
{
  const float* x   = (const float*)d_in[0];
  const float* h0  = (const float*)d_in[1];
  const float* c0  = (const float*)d_in[2];
  const float* A   = (const float*)d_in[3];
  const float* ei  = (const float*)d_in[4];
  const float* wg0 = (const float*)d_in[5];
  const float* bg0 = (const float*)d_in[6];
  const float* wg1 = (const float*)d_in[7];
  const float* bg1 = (const float*)d_in[8];
  const float* wr1 = (const float*)d_in[9];
  const float* br1 = (const float*)d_in[10];
  const float* kern  = (const float*)d_in[11];
  const float* kernB = (const float*)d_in[12];
  const float* kernW = (const float*)d_in[13];
  const float* rk    = (const float*)d_in[14];
  const float* rkB   = (const float*)d_in[15];
  const float* rkW   = (const float*)d_in[16];
  const float* bias  = (const float*)d_in[17];
  const float* biasB = (const float*)d_in[18];
  const float* biasW = (const float*)d_in[19];
  float* out = (float*)d_out;
  float* ws  = (float*)d_ws;

  // ws layout (floats), total 39,321,600 = 157.3 MB (== round-0 proven size):
  float* feat = ws;                                   // 102400*256 = 26,214,400
  float* ycat = ws + (size_t)26214400;                // 25600*384  =  9,830,400
  float* xcat = ycat;                                 // 25600*192 overlays ycat (dead before ycat written)
  float* yc   = ws + (size_t)26214400 + 9830400;      // 25600*128  =  3,276,800

  for(int c=0;c<NCH;++c){
    const float* xc = x + (size_t)c*NnC*(Vv*Dd);
    kMix<64> <<<NnC, 192, 0, stream>>>(xc, A, ei, 0,    xcat);
    kGemm<1> <<<dim3(RC/64,1), 256, 0, stream>>>(xcat, nullptr, wg0, nullptr, bg0, nullptr, A, ei, yc);
    kMix<128><<<NnC, 384, 0, stream>>>(yc, A, ei, 1875, ycat);
    kGemm<2> <<<dim3(RC/64,2), 256, 0, stream>>>(ycat, yc, wg1, wr1, bg1, br1, A, ei,
                                                 feat + (size_t)c*RC*256);
  }
  kLSTM<0,4><<<dim3(N3/64,4),256,0,stream>>>(feat,h0,c0,kern,rk,bias,out);
  kLSTM<1,2><<<dim3(Nn/32,4),256,0,stream>>>(feat,h0,c0,kernB,rkB,biasB,out);
  kLSTM<2,2><<<dim3(Bn/32,4),256,0,stream>>>(feat,h0,c0,kernW,rkW,biasW,out);
}

// Round 3
// 4668.246 us; speedup vs baseline: 3.1288x; 1.4447x over previous
//
#include <hip/hip_runtime.h>
#include <math.h>

// Problem constants
constexpr int Bn = 2048, Mm = 2, Vv = 25, Dd = 64;
constexpr int C1 = 128, C2 = 256, Kk = 3, Uu = 256;
constexpr int NJ = Mm*Vv*Uu;     // 12800
constexpr int NBd = Mm*Uu;       // 512
constexpr int SD = NJ+NBd+Uu;    // 13568
constexpr int Nn = Bn*Mm;        // 4096
constexpr int N3 = Nn*Vv;        // 102400
constexpr int NCH = 4;           // n-chunks (keeps ws at <=157.3 MB)
constexpr int NnC = Nn/NCH;      // 1024 n per chunk
constexpr int RC  = NnC*Vv;      // 25600 rows per chunk

__device__ __forceinline__ float hsig(float z){ return fminf(fmaxf(0.2f*z+0.5f,0.f),1.f); }

// ---------------------------------------------------------------------------
// kMix<SW>: v-mixing by adjacency, applied BEFORE the channel GEMM (commutes).
// ---------------------------------------------------------------------------
template<int SW>
__global__ __launch_bounds__(SW*3) void kMix(
    const float* __restrict__ src, const float* __restrict__ Amat,
    const float* __restrict__ ei, int eoff, float* __restrict__ dst)
{
  __shared__ float xs[Vv*SW];
  __shared__ float as[Kk*Vv*Vv];
  const int n = blockIdx.x, t = threadIdx.x;
  const float* srow = src + (size_t)n*(Vv*SW);
  for(int i=t;i<Vv*SW;i+=SW*3) xs[i]=srow[i];
  for(int i=t;i<Kk*Vv*Vv;i+=SW*3) as[i]=ei[eoff+i]*Amat[i];
  __syncthreads();
  const int k = t/SW, d = t%SW;
  float acc[Vv];
  #pragma unroll
  for(int w=0;w<Vv;++w) acc[w]=0.f;
  for(int v=0;v<Vv;++v){
    float xv = xs[v*SW+d];
    const float* ap = &as[k*625 + v*25];
    #pragma unroll
    for(int w=0;w<Vv;++w) acc[w] += ap[w]*xv;
  }
  float* drow = dst + (size_t)n*(Vv*3*SW);
  for(int w=0;w<Vv;++w) drow[w*(3*SW) + t] = acc[w];
}

// ---------------------------------------------------------------------------
// kGemm<MODE>: tiled fp32 GEMM + fused bias/relu epilogue (unchanged, verified).
// ---------------------------------------------------------------------------
template<int MODE>
__global__ __launch_bounds__(256,2) void kGemm(
    const float* __restrict__ A1, const float* __restrict__ A2,
    const float* __restrict__ W1, const float* __restrict__ W2,
    const float* __restrict__ bg, const float* __restrict__ br,
    const float* __restrict__ Amat, const float* __restrict__ ei,
    float* __restrict__ out)
{
  constexpr int KT = (MODE==1)?192:512;
  constexpr int NT = (MODE==1)?128:256;
  constexpr int EOFF = (MODE==1)?0:1875;
  __shared__ float As[64*33];
  __shared__ float Bs[32*128];
  __shared__ float asums[75];
  const int t = threadIdx.x;
  const int r0 = blockIdx.x*64, c0 = blockIdx.y*128;
  if(t<75){
    int k=t/25, w=t%25; float s=0.f;
    for(int v=0;v<25;++v) s += ei[EOFF + k*625+v*25+w]*Amat[k*625+v*25+w];
    asums[t]=s;
  }
  const int tx = t&15, ty = t>>4;
  float acc[4][8];
  #pragma unroll
  for(int i=0;i<4;++i)
    #pragma unroll
    for(int j=0;j<8;++j) acc[i][j]=0.f;

  for(int k0=0;k0<KT;k0+=32){
    __syncthreads();
    {
      int row = t>>2, kb = (t&3)*8;
      const float* src;
      if constexpr (MODE==1) src = A1 + (size_t)(r0+row)*192 + (k0+kb);
      else src = (k0<384) ? (A1 + (size_t)(r0+row)*384 + (k0+kb))
                          : (A2 + (size_t)(r0+row)*128 + (k0-384+kb));
      float4 v0 = *(const float4*)src;
      float4 v1 = *(const float4*)(src+4);
      float* dA = &As[row*33+kb];
      dA[0]=v0.x; dA[1]=v0.y; dA[2]=v0.z; dA[3]=v0.w;
      dA[4]=v1.x; dA[5]=v1.y; dA[6]=v1.z; dA[7]=v1.w;
    }
    #pragma unroll
    for(int i=0;i<4;++i){
      int f = i*1024 + t*4;
      int kk = f>>7, c4 = f&127;
      int kg = k0+kk;
      const float* wsrc;
      if constexpr (MODE==1){
        int pl = kg>>6, d = kg&63;
        wsrc = W1 + (size_t)d*384 + pl*128 + c4;
      } else {
        if(kg<384){ int pl = kg>>7, d = kg&127; wsrc = W1 + (size_t)d*768 + pl*256 + c0 + c4; }
        else      { wsrc = W2 + (size_t)(kg-384)*256 + c0 + c4; }
      }
      *(float4*)&Bs[kk*128+c4] = *(const float4*)wsrc;
    }
    __syncthreads();
    #pragma unroll
    for(int kk=0;kk<32;++kk){
      float4 b0 = *(const float4*)&Bs[kk*128 + tx*4];
      float4 b1 = *(const float4*)&Bs[kk*128 + 64 + tx*4];
      #pragma unroll
      for(int ri=0;ri<4;++ri){
        float av = As[(ty*4+ri)*33+kk];
        acc[ri][0]+=av*b0.x; acc[ri][1]+=av*b0.y; acc[ri][2]+=av*b0.z; acc[ri][3]+=av*b0.w;
        acc[ri][4]+=av*b1.x; acc[ri][5]+=av*b1.y; acc[ri][6]+=av*b1.z; acc[ri][7]+=av*b1.w;
      }
    }
  }
  #pragma unroll
  for(int ri=0;ri<4;++ri){
    int rg = r0 + ty*4 + ri;
    int w = rg % 25;
    float a0w = asums[w], a1w = asums[25+w], a2w = asums[50+w];
    #pragma unroll
    for(int half=0; half<2; ++half){
      float4 o;
      float* op = &o.x;
      #pragma unroll
      for(int ci=0;ci<4;++ci){
        int cg = c0 + half*64 + tx*4 + ci;
        float b;
        if constexpr (MODE==1) b = a0w*bg[cg] + a1w*bg[128+cg] + a2w*bg[256+cg];
        else                   b = br[cg] + a0w*bg[cg] + a1w*bg[256+cg] + a2w*bg[512+cg];
        op[ci] = fmaxf(acc[ri][half*4+ci] + b, 0.f);
      }
      *(float4*)&out[(size_t)rg*NT + c0 + half*64 + tx*4] = o;
    }
  }
}

// ---------------------------------------------------------------------------
// rowmap: MODE 0 joint, 1 body, 2 whole
// ---------------------------------------------------------------------------
template<int MODE>
__device__ __forceinline__ void rowmap(int row, int& hoff, int& boff){
  if(MODE==0){ int b=row/50; int j=row-b*50; hoff=b*SD + j*256; boff=j*1024; }
  else if(MODE==1){ int b=row>>1; int m=row&1; hoff=b*SD + NJ + m*256; boff=m*1024; }
  else { hoff=row*SD + NJ + NBd; boff=0; }
}

// ---------------------------------------------------------------------------
// kLSTM<0,4>: joint LSTM, direct (grid 1600x4 = 6400 blocks — occupancy OK).
// ---------------------------------------------------------------------------
template<int MODE, int RPT>
__global__ __launch_bounds__(256,2) void kLSTM(
    const float* __restrict__ feat, const float* __restrict__ h0, const float* __restrict__ c0,
    const float* __restrict__ Wm, const float* __restrict__ Wr,
    const float* __restrict__ bias, float* __restrict__ out)
{
  constexpr int BR = RPT*16;
  constexpr int KF = (MODE==0)?256:(MODE==1)?6400:12800;
  constexpr int KT = KF+256;
  __shared__ float As[BR*33];
  __shared__ float Bs[32*256];
  const int t = threadIdx.x;
  const int tx = t & 15, ty = t >> 4;
  const int r0 = blockIdx.x*BR;
  const int u0 = blockIdx.y*64;
  float acc[RPT][16];
  #pragma unroll
  for(int i=0;i<RPT;++i)
    #pragma unroll
    for(int j=0;j<16;++j) acc[i][j]=0.f;

  for(int k0=0;k0<KT;k0+=32){
    const bool isF = (k0<KF);
    #pragma unroll
    for(int i=0;i<BR/32;++i){
      int fidx = t + i*256;
      int row = fidx>>3, k4=(fidx&7)<<2;
      int rg = r0+row;
      const float* src;
      if(isF) src = feat + (size_t)rg*KF + (k0+k4);
      else { int hoff,boff; rowmap<MODE>(rg,hoff,boff); (void)boff; src = h0 + (size_t)hoff + (k0-KF+k4); }
      float4 v4 = *(const float4*)src;
      float* dst=&As[row*33+k4];
      dst[0]=v4.x; dst[1]=v4.y; dst[2]=v4.z; dst[3]=v4.w;
    }
    #pragma unroll
    for(int i=0;i<8;++i){
      int fidx=t+i*256;
      int kk=fidx>>6, j4=(fidx&63)<<2;
      int wcol=(j4>>6)*256 + u0 + (j4&63);
      const float* wsrc = isF ? (Wm + (size_t)(k0+kk)*1024 + wcol)
                              : (Wr + (size_t)(k0-KF+kk)*1024 + wcol);
      *(float4*)&Bs[kk*256+j4] = *(const float4*)wsrc;
    }
    __syncthreads();
    #pragma unroll
    for(int kk=0;kk<32;++kk){
      float a[RPT];
      #pragma unroll
      for(int ri=0;ri<RPT;++ri) a[ri]=As[(ty*RPT+ri)*33+kk];
      #pragma unroll
      for(int g=0;g<4;++g){
        float4 bv = *(const float4*)&Bs[kk*256 + g*64 + tx*4];
        #pragma unroll
        for(int ri=0;ri<RPT;++ri){
          acc[ri][g*4+0]+=a[ri]*bv.x;
          acc[ri][g*4+1]+=a[ri]*bv.y;
          acc[ri][g*4+2]+=a[ri]*bv.z;
          acc[ri][g*4+3]+=a[ri]*bv.w;
        }
      }
    }
    __syncthreads();
  }
  #pragma unroll
  for(int ri=0;ri<RPT;++ri){
    int rg = r0 + ty*RPT + ri;
    int hoff,boff; rowmap<MODE>(rg,hoff,boff);
    #pragma unroll
    for(int ui=0;ui<4;++ui){
      int u = u0 + tx*4 + ui;
      float zi = acc[ri][0+ui]  + bias[boff + u];
      float zf = acc[ri][4+ui]  + bias[boff + 256 + u];
      float zg = acc[ri][8+ui]  + bias[boff + 512 + u];
      float zo = acc[ri][12+ui] + bias[boff + 768 + u];
      float iv=hsig(zi), fv=hsig(zf), gv=tanhf(zg), ov=hsig(zo);
      float cc = c0[(size_t)hoff+u];
      float c2 = fv*cc + iv*gv;
      out[(size_t)hoff+u] = ov*tanhf(c2);
    }
  }
}

// ---------------------------------------------------------------------------
// kLSTMp<MODE>: split-K partial GEMM for body(1)/whole(2).
// Tile 32 rows x 256 gate cols, micro 4x8, K-chunk [z*KC, min(KT,(z+1)*KC)).
// Writes raw partial sums (no bias/activation) to part[z][row][1024].
// ---------------------------------------------------------------------------
template<int MODE>
__global__ __launch_bounds__(256,4) void kLSTMp(
    const float* __restrict__ feat, const float* __restrict__ h0,
    const float* __restrict__ Wm, const float* __restrict__ Wr,
    float* __restrict__ part, int KC)
{
  constexpr int KF = (MODE==1)?6400:12800;
  constexpr int KT = KF+256;
  constexpr int ROWS = (MODE==1)?4096:2048;
  __shared__ float As[32*33];
  __shared__ float Bs[32*256];
  const int t = threadIdx.x;
  const int tx = t&31, ty = t>>5;            // 32 lanes x 8 row-groups
  const int r0 = blockIdx.x*32;
  const int u0 = blockIdx.y*64;
  const int z  = blockIdx.z;
  const int kBeg = z*KC;
  const int kEnd = min(KT, kBeg+KC);
  float acc[4][8];
  #pragma unroll
  for(int i=0;i<4;++i)
    #pragma unroll
    for(int j=0;j<8;++j) acc[i][j]=0.f;

  for(int k0=kBeg;k0<kEnd;k0+=32){
    const bool isF = (k0<KF);
    __syncthreads();
    { // stage A: 32 rows x 32 k (1 float4/thread)
      int row = t>>3, k4 = (t&7)<<2;
      int rg = r0+row;
      const float* src;
      if(isF) src = feat + (size_t)rg*KF + (k0+k4);
      else { int hoff,boff; rowmap<MODE>(rg,hoff,boff); (void)boff; src = h0 + (size_t)hoff + (k0-KF+k4); }
      float4 v4 = *(const float4*)src;
      float* dst=&As[row*33+k4];
      dst[0]=v4.x; dst[1]=v4.y; dst[2]=v4.z; dst[3]=v4.w;
    }
    #pragma unroll
    for(int i=0;i<8;++i){ // stage B: 32 k x 256 cols (8 float4/thread)
      int fidx=t+i*256;                      // float4 index
      int kk=fidx>>6, j4=(fidx&63)<<2;
      int wcol=(j4>>6)*256 + u0 + (j4&63);
      const float* wsrc = isF ? (Wm + (size_t)(k0+kk)*1024 + wcol)
                              : (Wr + (size_t)(k0-KF+kk)*1024 + wcol);
      *(float4*)&Bs[kk*256+j4] = *(const float4*)wsrc;
    }
    __syncthreads();
    #pragma unroll
    for(int kk=0;kk<32;++kk){
      float4 b0 = *(const float4*)&Bs[kk*256 + tx*4];
      float4 b1 = *(const float4*)&Bs[kk*256 + 128 + tx*4];
      #pragma unroll
      for(int ri=0;ri<4;++ri){
        float av = As[(ty*4+ri)*33+kk];
        acc[ri][0]+=av*b0.x; acc[ri][1]+=av*b0.y; acc[ri][2]+=av*b0.z; acc[ri][3]+=av*b0.w;
        acc[ri][4]+=av*b1.x; acc[ri][5]+=av*b1.y; acc[ri][6]+=av*b1.z; acc[ri][7]+=av*b1.w;
      }
    }
  }
  // store partials: staged col j -> global gate col (j>>6)*256 + u0 + (j&63)
  #pragma unroll
  for(int ri=0;ri<4;++ri){
    int rg = r0 + ty*4 + ri;
    float* base = part + ((size_t)z*ROWS + rg)*1024;
    int lo = (tx>>4)*256 + u0 + ((tx*4)&63);       // cols j=tx*4..+3
    *(float4*)&base[lo]       = make_float4(acc[ri][0],acc[ri][1],acc[ri][2],acc[ri][3]);
    *(float4*)&base[512+lo]   = make_float4(acc[ri][4],acc[ri][5],acc[ri][6],acc[ri][7]); // j=128+tx*4 -> gate+2
  }
}

// ---------------------------------------------------------------------------
// kFin<MODE>: sum S partials + bias, LSTM pointwise, write h.
// grid = ROWS blocks x 256 threads (thread = one u).
// ---------------------------------------------------------------------------
template<int MODE>
__global__ __launch_bounds__(256) void kFin(
    const float* __restrict__ part, const float* __restrict__ c0,
    const float* __restrict__ bias, float* __restrict__ out, int S)
{
  constexpr int ROWS = (MODE==1)?4096:2048;
  const int row = blockIdx.x, u = threadIdx.x;
  int hoff,boff; rowmap<MODE>(row,hoff,boff);
  float zg4[4] = { bias[boff+u], bias[boff+256+u], bias[boff+512+u], bias[boff+768+u] };
  for(int s=0;s<S;++s){
    const float* p = part + ((size_t)s*ROWS + row)*1024;
    #pragma unroll
    for(int g=0;g<4;++g) zg4[g] += p[g*256+u];
  }
  float iv=hsig(zg4[0]), fv=hsig(zg4[1]), gv=tanhf(zg4[2]), ov=hsig(zg4[3]);
  float cc = c0[(size_t)hoff+u];
  float c2 = fv*cc + iv*gv;
  out[(size_t)hoff+u] = ov*tanhf(c2);
}

extern "C" void kernel_launch(void* const* d_in, const int* in_sizes, int n_in,
                              void* d_out, int out_size, void* d_ws, size_t ws_size,
                              hipStream_t stream)
{
  const float* x   = (const float*)d_in[0];
  const float* h0  = (const float*)d_in[1];
  const float* c0  = (const float*)d_in[2];
  const float* A   = (const float*)d_in[3];
  const float* ei  = (const float*)d_in[4];
  const float* wg0 = (const float*)d_in[5];
  const float* bg0 = (const float*)d_in[6];
  const float* wg1 = (const float*)d_in[7];
  const float* bg1 = (const float*)d_in[8];
  const float* wr1 = (const float*)d_in[9];
  const float* br1 = (const float*)d_in[10];
  const float* kern  = (const float*)d_in[11];
  const float* kernB = (const float*)d_in[12];
  const float* kernW = (const float*)d_in[13];
  const float* rk    = (const float*)d_in[14];
  const float* rkB   = (const float*)d_in[15];
  const float* rkW   = (const float*)d_in[16];
  const float* bias  = (const float*)d_in[17];
  const float* biasB = (const float*)d_in[18];
  const float* biasW = (const float*)d_in[19];
  float* out = (float*)d_out;
  float* ws  = (float*)d_ws;

  // ws layout (floats), max 38.8M = 155.2 MB (<= 157.3 MB proven):
  float* feat = ws;                                   // 26,214,400
  float* ycat = ws + (size_t)26214400;                // 9,830,400 (graph-conv phase only)
  float* xcat = ycat;                                 // overlays ycat
  float* yc   = ws + (size_t)26214400 + 9830400;      // 3,276,800 (graph-conv phase only)
  float* part = ws + (size_t)26214400;                // 12,582,912 (LSTM phase, overlays ycat/yc)

  for(int c=0;c<NCH;++c){
    const float* xc = x + (size_t)c*NnC*(Vv*Dd);
    kMix<64> <<<NnC, 192, 0, stream>>>(xc, A, ei, 0,    xcat);
    kGemm<1> <<<dim3(RC/64,1), 256, 0, stream>>>(xcat, nullptr, wg0, nullptr, bg0, nullptr, A, ei, yc);
    kMix<128><<<NnC, 384, 0, stream>>>(yc, A, ei, 1875, ycat);
    kGemm<2> <<<dim3(RC/64,2), 256, 0, stream>>>(ycat, yc, wg1, wr1, bg1, br1, A, ei,
                                                 feat + (size_t)c*RC*256);
  }
  // joint: unchanged direct kernel
  kLSTM<0,4><<<dim3(N3/64,4),256,0,stream>>>(feat,h0,c0,kern,rk,bias,out);
  // body: split-K S=3 (KC=2240: 2240+2240+2176 = 6656)
  kLSTMp<1><<<dim3(4096/32,4,3),256,0,stream>>>(feat,h0,kernB,rkB,part,2240);
  kFin<1> <<<4096,256,0,stream>>>(part,c0,biasB,out,3);
  // whole: split-K S=6 (KC=2176: 6*2176 = 13056)
  kLSTMp<2><<<dim3(2048/32,4,6),256,0,stream>>>(feat,h0,kernW,rkW,part,2176);
  kFin<2> <<<2048,256,0,stream>>>(part,c0,biasW,out,6);
}

// Round 5
// 1540.114 us; speedup vs baseline: 9.4838x; 3.0311x over previous
//
#include <hip/hip_runtime.h>
#include <hip/hip_bf16.h>
#include <math.h>

// Problem constants
constexpr int Bn = 2048, Mm = 2, Vv = 25, Dd = 64;
constexpr int C1 = 128, C2 = 256, Kk = 3, Uu = 256;
constexpr int NJ = Mm*Vv*Uu;     // 12800
constexpr int NBd = Mm*Uu;       // 512
constexpr int SD = NJ+NBd+Uu;    // 13568
constexpr int Nn = Bn*Mm;        // 4096
constexpr int N3 = Nn*Vv;        // 102400
constexpr int NCH = 4;
constexpr int NnC = Nn/NCH;      // 1024
constexpr int RC  = NnC*Vv;      // 25600

typedef __bf16 v8bf __attribute__((ext_vector_type(8)));
typedef float f32x16 __attribute__((ext_vector_type(16)));

__device__ __forceinline__ float hsig(float z){ return fminf(fmaxf(0.2f*z+0.5f,0.f),1.f); }
__device__ __forceinline__ unsigned short f2bs(float x){
  __hip_bfloat16 h = __float2bfloat16(x);
  unsigned short s; __builtin_memcpy(&s, &h, 2); return s;
}

// ---------------------------------------------------------------------------
// kMix<SW>: v-mixing by adjacency (unchanged, verified)
// ---------------------------------------------------------------------------
template<int SW>
__global__ __launch_bounds__(SW*3) void kMix(
    const float* __restrict__ src, const float* __restrict__ Amat,
    const float* __restrict__ ei, int eoff, float* __restrict__ dst)
{
  __shared__ float xs[Vv*SW];
  __shared__ float as[Kk*Vv*Vv];
  const int n = blockIdx.x, t = threadIdx.x;
  const float* srow = src + (size_t)n*(Vv*SW);
  for(int i=t;i<Vv*SW;i+=SW*3) xs[i]=srow[i];
  for(int i=t;i<Kk*Vv*Vv;i+=SW*3) as[i]=ei[eoff+i]*Amat[i];
  __syncthreads();
  const int k = t/SW, d = t%SW;
  float acc[Vv];
  #pragma unroll
  for(int w=0;w<Vv;++w) acc[w]=0.f;
  for(int v=0;v<Vv;++v){
    float xv = xs[v*SW+d];
    const float* ap = &as[k*625 + v*25];
    #pragma unroll
    for(int w=0;w<Vv;++w) acc[w] += ap[w]*xv;
  }
  float* drow = dst + (size_t)n*(Vv*3*SW);
  for(int w=0;w<Vv;++w) drow[w*(3*SW) + t] = acc[w];
}

// ---------------------------------------------------------------------------
// kGemm<MODE>: graph-conv GEMM + bias/relu. MODE1 -> fp32 y. MODE2 -> bf16 feat.
// ---------------------------------------------------------------------------
template<int MODE>
__global__ __launch_bounds__(256,2) void kGemm(
    const float* __restrict__ A1, const float* __restrict__ A2,
    const float* __restrict__ W1, const float* __restrict__ W2,
    const float* __restrict__ bg, const float* __restrict__ br,
    const float* __restrict__ Amat, const float* __restrict__ ei,
    void* __restrict__ outv)
{
  constexpr int KT = (MODE==1)?192:512;
  constexpr int NT = (MODE==1)?128:256;
  constexpr int EOFF = (MODE==1)?0:1875;
  __shared__ float As[64*33];
  __shared__ float Bs[32*128];
  __shared__ float asums[75];
  const int t = threadIdx.x;
  const int r0 = blockIdx.x*64, c0 = blockIdx.y*128;
  if(t<75){
    int k=t/25, w=t%25; float s=0.f;
    for(int v=0;v<25;++v) s += ei[EOFF + k*625+v*25+w]*Amat[k*625+v*25+w];
    asums[t]=s;
  }
  const int tx = t&15, ty = t>>4;
  float acc[4][8];
  #pragma unroll
  for(int i=0;i<4;++i)
    #pragma unroll
    for(int j=0;j<8;++j) acc[i][j]=0.f;

  for(int k0=0;k0<KT;k0+=32){
    __syncthreads();
    {
      int row = t>>2, kb = (t&3)*8;
      const float* src;
      if constexpr (MODE==1) src = A1 + (size_t)(r0+row)*192 + (k0+kb);
      else src = (k0<384) ? (A1 + (size_t)(r0+row)*384 + (k0+kb))
                          : (A2 + (size_t)(r0+row)*128 + (k0-384+kb));
      float4 v0 = *(const float4*)src;
      float4 v1 = *(const float4*)(src+4);
      float* dA = &As[row*33+kb];
      dA[0]=v0.x; dA[1]=v0.y; dA[2]=v0.z; dA[3]=v0.w;
      dA[4]=v1.x; dA[5]=v1.y; dA[6]=v1.z; dA[7]=v1.w;
    }
    #pragma unroll
    for(int i=0;i<4;++i){
      int f = i*1024 + t*4;
      int kk = f>>7, c4 = f&127;
      int kg = k0+kk;
      const float* wsrc;
      if constexpr (MODE==1){
        int pl = kg>>6, d = kg&63;
        wsrc = W1 + (size_t)d*384 + pl*128 + c4;
      } else {
        if(kg<384){ int pl = kg>>7, d = kg&127; wsrc = W1 + (size_t)d*768 + pl*256 + c0 + c4; }
        else      { wsrc = W2 + (size_t)(kg-384)*256 + c0 + c4; }
      }
      *(float4*)&Bs[kk*128+c4] = *(const float4*)wsrc;
    }
    __syncthreads();
    #pragma unroll
    for(int kk=0;kk<32;++kk){
      float4 b0 = *(const float4*)&Bs[kk*128 + tx*4];
      float4 b1 = *(const float4*)&Bs[kk*128 + 64 + tx*4];
      #pragma unroll
      for(int ri=0;ri<4;++ri){
        float av = As[(ty*4+ri)*33+kk];
        acc[ri][0]+=av*b0.x; acc[ri][1]+=av*b0.y; acc[ri][2]+=av*b0.z; acc[ri][3]+=av*b0.w;
        acc[ri][4]+=av*b1.x; acc[ri][5]+=av*b1.y; acc[ri][6]+=av*b1.z; acc[ri][7]+=av*b1.w;
      }
    }
  }
  #pragma unroll
  for(int ri=0;ri<4;++ri){
    int rg = r0 + ty*4 + ri;
    int w = rg % 25;
    float a0w = asums[w], a1w = asums[25+w], a2w = asums[50+w];
    #pragma unroll
    for(int half=0; half<2; ++half){
      float ov[4];
      #pragma unroll
      for(int ci=0;ci<4;++ci){
        int cg = c0 + half*64 + tx*4 + ci;
        float b;
        if constexpr (MODE==1) b = a0w*bg[cg] + a1w*bg[128+cg] + a2w*bg[256+cg];
        else                   b = br[cg] + a0w*bg[cg] + a1w*bg[256+cg] + a2w*bg[512+cg];
        ov[ci] = fmaxf(acc[ri][half*4+ci] + b, 0.f);
      }
      size_t oidx = (size_t)rg*NT + c0 + half*64 + tx*4;
      if constexpr (MODE==1){
        *(float4*)((float*)outv + oidx) = make_float4(ov[0],ov[1],ov[2],ov[3]);
      } else {
        uint2 o2;
        o2.x = (unsigned)f2bs(ov[0]) | ((unsigned)f2bs(ov[1])<<16);
        o2.y = (unsigned)f2bs(ov[2]) | ((unsigned)f2bs(ov[3])<<16);
        *(uint2*)((unsigned short*)outv + oidx) = o2;
      }
    }
  }
}

// ---------------------------------------------------------------------------
// hoffOf: MODE 0 joint, 1 body, 2 whole (h0/c0/out offset of a GEMM row)
// ---------------------------------------------------------------------------
template<int MODE>
__device__ __forceinline__ size_t hoffOf(int row){
  if constexpr (MODE==0){ int b=row/50, j=row-b*50; return (size_t)b*SD + j*256; }
  else if constexpr (MODE==1){ int b=row>>1, m=row&1; return (size_t)b*SD + NJ + m*256; }
  else return (size_t)row*SD + NJ + NBd;
}

// ---------------------------------------------------------------------------
// kConvW<MODE>: weights fp32 -> bf16, tile-contiguous layout
// out[ublk][kt][cc(256)][kk(32)], cc = (uu>>5)*128 + g*32 + (uu&31),
// source col = g*256 + ublk*64 + uu;  k = kt*32+kk (Wm if k<KF else Wr[k-KF]).
// ---------------------------------------------------------------------------
template<int MODE>
__global__ __launch_bounds__(256) void kConvW(
    const float* __restrict__ Wm, const float* __restrict__ Wr,
    unsigned short* __restrict__ out, int total)
{
  constexpr int KF = (MODE==0)?256:(MODE==1)?6400:12800;
  constexpr int NKT = (KF+256)/32;
  int i = blockIdx.x*256 + threadIdx.x;
  if(i>=total) return;
  int kk = i & 31;
  int cc = (i>>5) & 255;
  int kt = (i>>13) % NKT;
  int ublk = i/(NKT*8192);
  int k = kt*32+kk;
  int uu = ((cc>>7)<<5) + (cc&31);
  int g = (cc>>5)&3;
  int col = g*256 + ublk*64 + uu;
  float v = (k<KF) ? Wm[(size_t)k*1024+col] : Wr[(size_t)(k-KF)*1024+col];
  out[i] = f2bs(v);
}

// ---------------------------------------------------------------------------
// kLSTMm<MODE>: MFMA bf16 GEMM (64 rows x 256 staged cols/block, 4 waves 2x2,
// wave = 32 rows x 128 cols = 4 gate-tiles of 32x32, v_mfma_f32_32x32x16_bf16).
// MODE 0: fused LSTM epilogue -> out.  MODE 1/2: split-K partials -> part.
// ---------------------------------------------------------------------------
template<int MODE>
__global__ __launch_bounds__(256,2) void kLSTMm(
    const unsigned short* __restrict__ featb, const float* __restrict__ h0,
    const float* __restrict__ c0, const unsigned short* __restrict__ Wcat,
    const float* __restrict__ bias, float* __restrict__ outp, int KC)
{
  constexpr int KF = (MODE==0)?256:(MODE==1)?6400:12800;
  constexpr int KT = KF+256;
  constexpr int NKT = KT/32;
  constexpr int ROWS = (MODE==0)?N3:(MODE==1)?Nn:Bn;
  __shared__ unsigned short Al[64*40];   // pad 40 bf16 (80 B rows)
  __shared__ unsigned short Bl[256*40];
  const int t = threadIdx.x;
  const int r0 = blockIdx.x*64;
  const int ublk = blockIdx.y;
  const int z = (MODE==0)?0:blockIdx.z;
  const int kBeg = z*KC, kEnd = min(KT, kBeg+KC);
  const int lane = t&63, wid = t>>6;
  const int wr = wid>>1, w2 = wid&1;
  const int l31 = lane&31, l5 = lane>>5;
  const int sArow = t>>2, sAk8 = (t&3)*8;

  f32x16 acc[4];
  #pragma unroll
  for(int g=0; g<4; ++g)
    #pragma unroll
    for(int j=0; j<16; ++j) acc[g][j]=0.f;

  for(int k0=kBeg; k0<kEnd; k0+=32){
    // ---- stage A: 64 rows x 32 k (8 bf16/thread) ----
    {
      int rg = r0 + sArow;
      int kg = k0 + sAk8;
      uint4 av;
      if(kg < KF){
        av = *(const uint4*)(featb + (size_t)rg*KF + kg);
      } else {
        const float* hs = h0 + hoffOf<MODE>(rg) + (kg - KF);
        float4 f0 = *(const float4*)hs;
        float4 f1 = *(const float4*)(hs+4);
        av.x = (unsigned)f2bs(f0.x) | ((unsigned)f2bs(f0.y)<<16);
        av.y = (unsigned)f2bs(f0.z) | ((unsigned)f2bs(f0.w)<<16);
        av.z = (unsigned)f2bs(f1.x) | ((unsigned)f2bs(f1.y)<<16);
        av.w = (unsigned)f2bs(f1.z) | ((unsigned)f2bs(f1.w)<<16);
      }
      *(uint4*)&Al[sArow*40 + sAk8] = av;
    }
    // ---- stage B: one 256x32 pre-arranged tile (16 KB, 4 x uint4/thread) ----
    // f indexes uint4s; each staged-col row (stride 40) holds 32 bf16 = 4 uint4s:
    // row = f>>2, in-row offset = (f&3)*8.   [round-4 fix: was (f>>3)/(f&7) —
    // left rows 128..255 uninitialized -> NaN]
    {
      const unsigned short* wt = Wcat + ((size_t)ublk*NKT + (k0>>5))*8192;
      #pragma unroll
      for(int i=0;i<4;++i){
        int f = i*256 + t;
        *(uint4*)&Bl[(f>>2)*40 + (f&3)*8] = *(const uint4*)(wt + f*8);
      }
    }
    __syncthreads();
    const unsigned short* Ab = &Al[(wr*32 + l31)*40 + l5*8];
    const unsigned short* Bb = &Bl[(w2*128 + l31)*40 + l5*8];
    #pragma unroll
    for(int kh=0; kh<2; ++kh){
      v8bf a = *(const v8bf*)(Ab + kh*16);
      #pragma unroll
      for(int g=0; g<4; ++g){
        v8bf b = *(const v8bf*)(Bb + g*32*40 + kh*16);
        acc[g] = __builtin_amdgcn_mfma_f32_32x32x16_bf16(a, b, acc[g], 0, 0, 0);
      }
    }
    __syncthreads();
  }

  const int uu = w2*32 + l31;
  const int u  = ublk*64 + uu;
  if constexpr (MODE==0){
    #pragma unroll
    for(int reg=0; reg<16; ++reg){
      int row = r0 + wr*32 + (reg&3) + 8*(reg>>2) + 4*l5;
      int b = row/50, j = row - b*50;
      size_t hoff = (size_t)b*SD + j*256;
      int boff = j*1024;
      float zi = acc[0][reg] + bias[boff + u];
      float zf = acc[1][reg] + bias[boff + 256 + u];
      float zg = acc[2][reg] + bias[boff + 512 + u];
      float zo = acc[3][reg] + bias[boff + 768 + u];
      float iv=hsig(zi), fv=hsig(zf), gv=tanhf(zg), ov=hsig(zo);
      float cc = c0[hoff+u];
      float c2 = fv*cc + iv*gv;
      outp[hoff+u] = ov*tanhf(c2);
    }
  } else {
    #pragma unroll
    for(int reg=0; reg<16; ++reg){
      int row = r0 + wr*32 + (reg&3) + 8*(reg>>2) + 4*l5;
      float* base = outp + ((size_t)z*ROWS + row)*1024 + u;
      base[0]   = acc[0][reg];
      base[256] = acc[1][reg];
      base[512] = acc[2][reg];
      base[768] = acc[3][reg];
    }
  }
}

// ---------------------------------------------------------------------------
// kFin<MODE>: sum S partials + bias, LSTM pointwise (unchanged, verified)
// ---------------------------------------------------------------------------
template<int MODE>
__global__ __launch_bounds__(256) void kFin(
    const float* __restrict__ part, const float* __restrict__ c0,
    const float* __restrict__ bias, float* __restrict__ out, int S)
{
  constexpr int ROWS = (MODE==1)?Nn:Bn;
  const int row = blockIdx.x, u = threadIdx.x;
  size_t hoff = hoffOf<MODE>(row);
  int boff = (MODE==1)?((row&1)*1024):0;
  float zg4[4] = { bias[boff+u], bias[boff+256+u], bias[boff+512+u], bias[boff+768+u] };
  for(int s=0;s<S;++s){
    const float* p = part + ((size_t)s*ROWS + row)*1024;
    #pragma unroll
    for(int g=0;g<4;++g) zg4[g] += p[g*256+u];
  }
  float iv=hsig(zg4[0]), fv=hsig(zg4[1]), gv=tanhf(zg4[2]), ov=hsig(zg4[3]);
  float cc = c0[hoff+u];
  float c2 = fv*cc + iv*gv;
  out[hoff+u] = ov*tanhf(c2);
}

extern "C" void kernel_launch(void* const* d_in, const int* in_sizes, int n_in,
                              void* d_out, int out_size, void* d_ws, size_t ws_size,
                              hipStream_t stream)
{
  const float* x   = (const float*)d_in[0];
  const float* h0  = (const float*)d_in[1];
  const float* c0  = (const float*)d_in[2];
  const float* A   = (const float*)d_in[3];
  const float* ei  = (const float*)d_in[4];
  const float* wg0 = (const float*)d_in[5];
  const float* bg0 = (const float*)d_in[6];
  const float* wg1 = (const float*)d_in[7];
  const float* bg1 = (const float*)d_in[8];
  const float* wr1 = (const float*)d_in[9];
  const float* br1 = (const float*)d_in[10];
  const float* kern  = (const float*)d_in[11];
  const float* kernB = (const float*)d_in[12];
  const float* kernW = (const float*)d_in[13];
  const float* rk    = (const float*)d_in[14];
  const float* rkB   = (const float*)d_in[15];
  const float* rkW   = (const float*)d_in[16];
  const float* bias  = (const float*)d_in[17];
  const float* biasB = (const float*)d_in[18];
  const float* biasW = (const float*)d_in[19];
  float* out = (float*)d_out;
  char* wsb  = (char*)d_ws;

  // ws layout (bytes), total 138.4 MB (< 157.3 MB proven):
  //  [0, 52428800)            featb (bf16, 102400x256)
  //  [52428800, 104857600)    graph-conv: xcat/ycat (39321600 B) + yc (13107200 B)
  //                           then (overlaid): WbJ 1 MB | WbB 13.6 MB | WbW 26.7 MB
  //  [104857600, 138412032)   part (fp32 split-K partials, 33.5 MB)
  unsigned short* featb = (unsigned short*)wsb;
  float* xcat = (float*)(wsb + 52428800);
  float* ycat = xcat;
  float* yc   = (float*)(wsb + 52428800 + 39321600);
  unsigned short* WbJ = (unsigned short*)(wsb + 52428800);
  unsigned short* WbB = WbJ + 524288;
  unsigned short* WbW = WbB + 6815744;
  float* part = (float*)(wsb + 104857600);

  for(int c=0;c<NCH;++c){
    const float* xc = x + (size_t)c*NnC*(Vv*Dd);
    kMix<64> <<<NnC, 192, 0, stream>>>(xc, A, ei, 0,    xcat);
    kGemm<1> <<<dim3(RC/64,1), 256, 0, stream>>>(xcat, nullptr, wg0, nullptr, bg0, nullptr, A, ei, yc);
    kMix<128><<<NnC, 384, 0, stream>>>(yc, A, ei, 1875, ycat);
    kGemm<2> <<<dim3(RC/64,2), 256, 0, stream>>>(ycat, yc, wg1, wr1, bg1, br1, A, ei,
                                                 featb + (size_t)c*RC*256);
  }
  // weights -> bf16 tile layout (after graph-conv; overlays ycat/yc)
  kConvW<0><<<524288/256,   256, 0, stream>>>(kern,  rk,  WbJ, 524288);
  kConvW<1><<<6815744/256,  256, 0, stream>>>(kernB, rkB, WbB, 6815744);
  kConvW<2><<<13369344/256, 256, 0, stream>>>(kernW, rkW, WbW, 13369344);
  // joint: direct MFMA + fused LSTM epilogue
  kLSTMm<0><<<dim3(N3/64,4),   256, 0, stream>>>(featb, h0, c0, WbJ, bias, out, 512);
  // body: split-K S=2 (KC=3456, KT=6912)
  kLSTMm<1><<<dim3(Nn/64,4,2), 256, 0, stream>>>(featb, h0, nullptr, WbB, nullptr, part, 3456);
  kFin<1><<<Nn, 256, 0, stream>>>(part, c0, biasB, out, 2);
  // whole: split-K S=4 (KC=3328, KT=13312)
  kLSTMm<2><<<dim3(Bn/64,4,4), 256, 0, stream>>>(featb, h0, nullptr, WbW, nullptr, part, 3328);
  kFin<2><<<Bn, 256, 0, stream>>>(part, c0, biasW, out, 4);
}

// Round 7
// 1115.771 us; speedup vs baseline: 13.0907x; 1.3803x over previous
//
#include <hip/hip_runtime.h>
#include <hip/hip_bf16.h>
#include <math.h>

// Problem constants
constexpr int Bn = 2048, Mm = 2, Vv = 25, Dd = 64;
constexpr int C1 = 128, C2 = 256, Kk = 3, Uu = 256;
constexpr int NJ = Mm*Vv*Uu;     // 12800
constexpr int NBd = Mm*Uu;       // 512
constexpr int SD = NJ+NBd+Uu;    // 13568
constexpr int Nn = Bn*Mm;        // 4096
constexpr int N3 = Nn*Vv;        // 102400
constexpr int NCH = 2;
constexpr int NnC = Nn/NCH;      // 2048
constexpr int RCn = NnC*Vv;      // 51200 rows per chunk

typedef __bf16 v8bf __attribute__((ext_vector_type(8)));
typedef float f32x16 __attribute__((ext_vector_type(16)));

__device__ __forceinline__ float hsig(float z){ return fminf(fmaxf(0.2f*z+0.5f,0.f),1.f); }
__device__ __forceinline__ unsigned short f2bs(float x){
  __hip_bfloat16 h = __float2bfloat16(x);
  unsigned short s; __builtin_memcpy(&s, &h, 2); return s;
}
__device__ __forceinline__ float bs2f(unsigned short s){
  unsigned u = ((unsigned)s)<<16; float f; __builtin_memcpy(&f,&u,4); return f;
}

// ---------------------------------------------------------------------------
// kMix<SW,TI>: v-mixing by adjacency. Input fp32 (SW=64) or bf16 (SW=128),
// output bf16.
// ---------------------------------------------------------------------------
template<int SW, typename TI>
__global__ __launch_bounds__(SW*3) void kMix(
    const TI* __restrict__ src, const float* __restrict__ Amat,
    const float* __restrict__ ei, int eoff, unsigned short* __restrict__ dst)
{
  __shared__ float xs[Vv*SW];
  __shared__ float as[Kk*Vv*Vv];
  const int n = blockIdx.x, t = threadIdx.x;
  const TI* srow = src + (size_t)n*(Vv*SW);
  for(int i=t;i<Vv*SW;i+=SW*3){
    if constexpr (sizeof(TI)==2) xs[i]=bs2f((unsigned short)srow[i]);
    else xs[i]=srow[i];
  }
  for(int i=t;i<Kk*Vv*Vv;i+=SW*3) as[i]=ei[eoff+i]*Amat[i];
  __syncthreads();
  const int k = t/SW, d = t%SW;
  float acc[Vv];
  #pragma unroll
  for(int w=0;w<Vv;++w) acc[w]=0.f;
  for(int v=0;v<Vv;++v){
    float xv = xs[v*SW+d];
    const float* ap = &as[k*625 + v*25];
    #pragma unroll
    for(int w=0;w<Vv;++w) acc[w] += ap[w]*xv;
  }
  unsigned short* drow = dst + (size_t)n*(Vv*3*SW);
  for(int w=0;w<Vv;++w) drow[w*(3*SW) + t] = f2bs(acc[w]);
}

// ---------------------------------------------------------------------------
// hoffOf: MODE 0 joint, 1 body, 2 whole (h0/c0/out offset of a GEMM row)
// ---------------------------------------------------------------------------
template<int MODE>
__device__ __forceinline__ size_t hoffOf(int row){
  if constexpr (MODE==0){ int b=row/50, j=row-b*50; return (size_t)b*SD + j*256; }
  else if constexpr (MODE==1){ int b=row>>1, m=row&1; return (size_t)b*SD + NJ + m*256; }
  else return (size_t)row*SD + NJ + NBd;
}

// ---------------------------------------------------------------------------
// kConvW<MODE>: weights fp32 -> bf16 in MFMA FRAGMENT order.
// Fragment layout (per k-tile of 32): frag fb = cg*2+kh, lane ln, elem e:
//   staged col = cg*32+(ln&31), k = kt*32 + (ln>>5)*8 + kh*16 + e.
// MODE 0/1/2 (LSTM): per [ublk][kt] 8192 shorts; staged col cc: cg = w2*4+g,
//   col = g*256 + ublk*64 + (cg>>2)*32 + (ln&31).  (lane holds all 4 gates of u)
// MODE 3 (graph GEMM2, K=512, N=256): col = cg*32+l31 direct.
// MODE 4 (graph GEMM1, K=192, N=128): NF=8.
// ---------------------------------------------------------------------------
template<int MODE>
__global__ __launch_bounds__(256) void kConvW(
    const float* __restrict__ Wm, const float* __restrict__ Wr,
    unsigned short* __restrict__ out, int total)
{
  int i = blockIdx.x*256 + threadIdx.x;
  if(i>=total) return;
  int e = i&7, ln = (i>>3)&63, l31 = ln&31, l5 = ln>>5;
  float v;
  if constexpr (MODE<=2){
    constexpr int KF = (MODE==0)?256:(MODE==1)?6400:12800;
    constexpr int NKT = (KF+256)/32;
    int fb = (i>>9)&15, kt = (i>>13)%NKT, ublk = i/(NKT*8192);
    int kh = fb&1, cg = fb>>1;
    int k = kt*32 + l5*8 + kh*16 + e;
    int g = cg&3, uu = (cg>>2)*32 + l31;
    int col = g*256 + ublk*64 + uu;
    v = (k<KF) ? Wm[(size_t)k*1024+col] : Wr[(size_t)(k-KF)*1024+col];
  } else if constexpr (MODE==3){
    int fb = (i>>9)&15, kt = i>>13;
    int kh = fb&1, cg = fb>>1;
    int k = kt*32 + l5*8 + kh*16 + e;
    int col = cg*32 + l31;
    v = (k<384) ? Wm[(size_t)(k&127)*768 + (k>>7)*256 + col]
                : Wr[(size_t)(k-384)*256 + col];
  } else {
    int fb = (i>>9)&7, kt = i>>12;
    int kh = fb&1, cg = fb>>1;
    int k = kt*32 + l5*8 + kh*16 + e;
    int col = cg*32 + l31;
    v = Wm[(size_t)(k&63)*384 + (k>>6)*128 + col];
  }
  out[i] = f2bs(v);
}

// ---------------------------------------------------------------------------
// kLSTMm<MODE>: MFMA bf16 GEMM, block tile 128 rows x 256 staged cols,
// 4 waves (2 row x 2 col), wave tile 64x128 (2 rowgroups x 4 gate-tiles).
// Fragment-linear LDS: A frag fa=(rg32*2+kh), B frag fb=(cg*2+kh); every
// ds read/write is frag*1KB + lane*16B -> conflict-free.
// MODE 0: fused LSTM epilogue -> out.  MODE 1/2: split-K partials -> part.
// ---------------------------------------------------------------------------
template<int MODE>
__global__ __launch_bounds__(256,2) void kLSTMm(
    const unsigned short* __restrict__ featb, const float* __restrict__ h0,
    const float* __restrict__ c0, const unsigned short* __restrict__ Wcat,
    const float* __restrict__ bias, float* __restrict__ outp, int KC)
{
  constexpr int KF = (MODE==0)?256:(MODE==1)?6400:12800;
  constexpr int KT = KF+256;
  constexpr int NKT = KT/32;
  constexpr int ROWS = (MODE==0)?N3:(MODE==1)?Nn:Bn;
  __shared__ unsigned short Afr[8*512];    // 8 KB
  __shared__ unsigned short Bfr[16*512];   // 16 KB
  const int t = threadIdx.x;
  const int r0 = blockIdx.x*128;
  const int ublk = blockIdx.y;
  const int z = (MODE==0)?0:blockIdx.z;
  const int kBeg = z*KC, kEnd = min(KT, kBeg+KC);
  const int lane = t&63, wid = t>>6;
  const int wr = wid>>1, w2 = wid&1;
  const int l31 = lane&31, l5 = lane>>5;

  f32x16 acc[2][4];
  #pragma unroll
  for(int rg=0;rg<2;++rg)
    #pragma unroll
    for(int g=0;g<4;++g)
      #pragma unroll
      for(int j=0;j<16;++j) acc[rg][g][j]=0.f;

  for(int k0=kBeg; k0<kEnd; k0+=32){
    // ---- stage A: 128 rows x 32 k, fragment order (2 uint4/thread) ----
    #pragma unroll
    for(int i=0;i<2;++i){
      int fi = i*256 + t;                      // [rg32:2][kh:1][ln:6]
      int ln = fi&63;
      int row = r0 + (fi>>7)*32 + (ln&31);
      int kc = (ln>>5) + ((fi>>6)&1)*2;
      int kg = k0 + kc*8;
      uint4 av;
      if(kg < KF){
        av = *(const uint4*)(featb + (size_t)row*KF + kg);
      } else {
        const float* hs = h0 + hoffOf<MODE>(row) + (kg - KF);
        float4 f0 = *(const float4*)hs;
        float4 f1 = *(const float4*)(hs+4);
        av.x = (unsigned)f2bs(f0.x) | ((unsigned)f2bs(f0.y)<<16);
        av.y = (unsigned)f2bs(f0.z) | ((unsigned)f2bs(f0.w)<<16);
        av.z = (unsigned)f2bs(f1.x) | ((unsigned)f2bs(f1.y)<<16);
        av.w = (unsigned)f2bs(f1.z) | ((unsigned)f2bs(f1.w)<<16);
      }
      *(uint4*)&Afr[fi*8] = av;
    }
    // ---- stage B: pre-permuted tile, pure linear copy (4 uint4/thread) ----
    {
      const unsigned short* wt = Wcat + ((size_t)ublk*NKT + (k0>>5))*8192;
      #pragma unroll
      for(int i=0;i<4;++i){
        int fi = i*256 + t;
        *(uint4*)&Bfr[fi*8] = *(const uint4*)(wt + fi*8);
      }
    }
    __syncthreads();
    #pragma unroll
    for(int kh=0; kh<2; ++kh){
      v8bf a0 = *(const v8bf*)&Afr[((wr*2+0)*2+kh)*512 + lane*8];
      v8bf a1 = *(const v8bf*)&Afr[((wr*2+1)*2+kh)*512 + lane*8];
      #pragma unroll
      for(int g=0; g<4; ++g){
        v8bf b = *(const v8bf*)&Bfr[((w2*4+g)*2+kh)*512 + lane*8];
        acc[0][g] = __builtin_amdgcn_mfma_f32_32x32x16_bf16(a0, b, acc[0][g], 0, 0, 0);
        acc[1][g] = __builtin_amdgcn_mfma_f32_32x32x16_bf16(a1, b, acc[1][g], 0, 0, 0);
      }
    }
    __syncthreads();
  }

  const int u = ublk*64 + w2*32 + l31;
  if constexpr (MODE==0){
    #pragma unroll
    for(int rg=0;rg<2;++rg){
      #pragma unroll
      for(int reg=0; reg<16; ++reg){
        int row = r0 + wr*64 + rg*32 + (reg&3) + 8*(reg>>2) + 4*l5;
        int b = row/50, j = row - b*50;
        size_t hoff = (size_t)b*SD + j*256;
        int boff = j*1024;
        float zi = acc[rg][0][reg] + bias[boff + u];
        float zf = acc[rg][1][reg] + bias[boff + 256 + u];
        float zg = acc[rg][2][reg] + bias[boff + 512 + u];
        float zo = acc[rg][3][reg] + bias[boff + 768 + u];
        float iv=hsig(zi), fv=hsig(zf), gv=tanhf(zg), ov=hsig(zo);
        float cc = c0[hoff+u];
        float c2 = fv*cc + iv*gv;
        outp[hoff+u] = ov*tanhf(c2);
      }
    }
  } else {
    #pragma unroll
    for(int rg=0;rg<2;++rg){
      #pragma unroll
      for(int reg=0; reg<16; ++reg){
        int row = r0 + wr*64 + rg*32 + (reg&3) + 8*(reg>>2) + 4*l5;
        float* base = outp + ((size_t)z*ROWS + row)*1024 + u;
        base[0]   = acc[rg][0][reg];
        base[256] = acc[rg][1][reg];
        base[512] = acc[rg][2][reg];
        base[768] = acc[rg][3][reg];
      }
    }
  }
}

// ---------------------------------------------------------------------------
// kGC2: graph GEMM2, MFMA. feat = relu([ycat|y] @ Wc2 + bias1(w,c)), bf16 out.
// Same 128x256 fragment structure as kLSTMm.
// ---------------------------------------------------------------------------
__global__ __launch_bounds__(256,2) void kGC2(
    const unsigned short* __restrict__ ycat, const unsigned short* __restrict__ yb,
    const unsigned short* __restrict__ Wc2, const float* __restrict__ bg1,
    const float* __restrict__ br1, const float* __restrict__ Amat,
    const float* __restrict__ ei, unsigned short* __restrict__ featb)
{
  __shared__ unsigned short Afr[8*512];
  __shared__ unsigned short Bfr[16*512];
  __shared__ float asums[75];
  const int t = threadIdx.x;
  const int r0 = blockIdx.x*128;
  if(t<75){
    int k=t/25, w=t%25; float s=0.f;
    for(int v=0;v<25;++v) s += ei[1875 + k*625+v*25+w]*Amat[k*625+v*25+w];
    asums[t]=s;
  }
  const int lane = t&63, wid = t>>6;
  const int wr = wid>>1, w2 = wid&1;
  const int l31 = lane&31, l5 = lane>>5;
  f32x16 acc[2][4];
  #pragma unroll
  for(int rg=0;rg<2;++rg)
    #pragma unroll
    for(int g=0;g<4;++g)
      #pragma unroll
      for(int j=0;j<16;++j) acc[rg][g][j]=0.f;

  for(int k0=0; k0<512; k0+=32){
    #pragma unroll
    for(int i=0;i<2;++i){
      int fi = i*256 + t;
      int ln = fi&63;
      int row = r0 + (fi>>7)*32 + (ln&31);
      int kc = (ln>>5) + ((fi>>6)&1)*2;
      int kg = k0 + kc*8;
      uint4 av = (kg<384) ? *(const uint4*)(ycat + (size_t)row*384 + kg)
                          : *(const uint4*)(yb   + (size_t)row*128 + (kg-384));
      *(uint4*)&Afr[fi*8] = av;
    }
    {
      const unsigned short* wt = Wc2 + (size_t)(k0>>5)*8192;
      #pragma unroll
      for(int i=0;i<4;++i){
        int fi = i*256 + t;
        *(uint4*)&Bfr[fi*8] = *(const uint4*)(wt + fi*8);
      }
    }
    __syncthreads();
    #pragma unroll
    for(int kh=0; kh<2; ++kh){
      v8bf a0 = *(const v8bf*)&Afr[((wr*2+0)*2+kh)*512 + lane*8];
      v8bf a1 = *(const v8bf*)&Afr[((wr*2+1)*2+kh)*512 + lane*8];
      #pragma unroll
      for(int g=0; g<4; ++g){
        v8bf b = *(const v8bf*)&Bfr[((w2*4+g)*2+kh)*512 + lane*8];
        acc[0][g] = __builtin_amdgcn_mfma_f32_32x32x16_bf16(a0, b, acc[0][g], 0, 0, 0);
        acc[1][g] = __builtin_amdgcn_mfma_f32_32x32x16_bf16(a1, b, acc[1][g], 0, 0, 0);
      }
    }
    __syncthreads();
  }
  #pragma unroll
  for(int rg=0;rg<2;++rg){
    #pragma unroll
    for(int reg=0; reg<16; ++reg){
      int row = r0 + wr*64 + rg*32 + (reg&3) + 8*(reg>>2) + 4*l5;
      int w = row % 25;
      float a0w = asums[w], a1w = asums[25+w], a2w = asums[50+w];
      #pragma unroll
      for(int g=0; g<4; ++g){
        int cc = w2*128 + g*32 + l31;
        float b = br1[cc] + a0w*bg1[cc] + a1w*bg1[256+cc] + a2w*bg1[512+cc];
        featb[(size_t)row*256 + cc] = f2bs(fmaxf(acc[rg][g][reg] + b, 0.f));
      }
    }
  }
}

// ---------------------------------------------------------------------------
// kGC1: graph GEMM1, MFMA. y = relu(xcat @ Wc1 + bias0(w,c)), bf16 out.
// Block tile 128x128, wave tile 64x64 (2 rowgroups x 2 col-tiles).
// ---------------------------------------------------------------------------
__global__ __launch_bounds__(256,2) void kGC1(
    const unsigned short* __restrict__ xcat, const unsigned short* __restrict__ Wc1,
    const float* __restrict__ bg0, const float* __restrict__ Amat,
    const float* __restrict__ ei, unsigned short* __restrict__ yb)
{
  __shared__ unsigned short Afr[8*512];
  __shared__ unsigned short Bfr[8*512];
  __shared__ float asums[75];
  const int t = threadIdx.x;
  const int r0 = blockIdx.x*128;
  if(t<75){
    int k=t/25, w=t%25; float s=0.f;
    for(int v=0;v<25;++v) s += ei[k*625+v*25+w]*Amat[k*625+v*25+w];
    asums[t]=s;
  }
  const int lane = t&63, wid = t>>6;
  const int wr = wid>>1, w2 = wid&1;
  const int l31 = lane&31, l5 = lane>>5;
  f32x16 acc[2][2];
  #pragma unroll
  for(int rg=0;rg<2;++rg)
    #pragma unroll
    for(int g=0;g<2;++g)
      #pragma unroll
      for(int j=0;j<16;++j) acc[rg][g][j]=0.f;

  for(int k0=0; k0<192; k0+=32){
    #pragma unroll
    for(int i=0;i<2;++i){
      int fi = i*256 + t;
      int ln = fi&63;
      int row = r0 + (fi>>7)*32 + (ln&31);
      int kc = (ln>>5) + ((fi>>6)&1)*2;
      int kg = k0 + kc*8;
      *(uint4*)&Afr[fi*8] = *(const uint4*)(xcat + (size_t)row*192 + kg);
    }
    {
      const unsigned short* wt = Wc1 + (size_t)(k0>>5)*4096;
      #pragma unroll
      for(int i=0;i<2;++i){
        int fi = i*256 + t;
        *(uint4*)&Bfr[fi*8] = *(const uint4*)(wt + fi*8);
      }
    }
    __syncthreads();
    #pragma unroll
    for(int kh=0; kh<2; ++kh){
      v8bf a0 = *(const v8bf*)&Afr[((wr*2+0)*2+kh)*512 + lane*8];
      v8bf a1 = *(const v8bf*)&Afr[((wr*2+1)*2+kh)*512 + lane*8];
      #pragma unroll
      for(int g=0; g<2; ++g){
        v8bf b = *(const v8bf*)&Bfr[((w2*2+g)*2+kh)*512 + lane*8];
        acc[0][g] = __builtin_amdgcn_mfma_f32_32x32x16_bf16(a0, b, acc[0][g], 0, 0, 0);
        acc[1][g] = __builtin_amdgcn_mfma_f32_32x32x16_bf16(a1, b, acc[1][g], 0, 0, 0);
      }
    }
    __syncthreads();
  }
  #pragma unroll
  for(int rg=0;rg<2;++rg){
    #pragma unroll
    for(int reg=0; reg<16; ++reg){
      int row = r0 + wr*64 + rg*32 + (reg&3) + 8*(reg>>2) + 4*l5;
      int w = row % 25;
      float a0w = asums[w], a1w = asums[25+w], a2w = asums[50+w];
      #pragma unroll
      for(int g=0; g<2; ++g){
        int cc = w2*64 + g*32 + l31;
        float b = a0w*bg0[cc] + a1w*bg0[128+cc] + a2w*bg0[256+cc];
        yb[(size_t)row*128 + cc] = f2bs(fmaxf(acc[rg][g][reg] + b, 0.f));
      }
    }
  }
}

// ---------------------------------------------------------------------------
// kFin<MODE>: sum S partials + bias, LSTM pointwise (unchanged, verified)
// ---------------------------------------------------------------------------
template<int MODE>
__global__ __launch_bounds__(256) void kFin(
    const float* __restrict__ part, const float* __restrict__ c0,
    const float* __restrict__ bias, float* __restrict__ out, int S)
{
  constexpr int ROWS = (MODE==1)?Nn:Bn;
  const int row = blockIdx.x, u = threadIdx.x;
  size_t hoff = hoffOf<MODE>(row);
  int boff = (MODE==1)?((row&1)*1024):0;
  float zg4[4] = { bias[boff+u], bias[boff+256+u], bias[boff+512+u], bias[boff+768+u] };
  for(int s=0;s<S;++s){
    const float* p = part + ((size_t)s*ROWS + row)*1024;
    #pragma unroll
    for(int g=0;g<4;++g) zg4[g] += p[g*256+u];
  }
  float iv=hsig(zg4[0]), fv=hsig(zg4[1]), gv=tanhf(zg4[2]), ov=hsig(zg4[3]);
  float cc = c0[hoff+u];
  float c2 = fv*cc + iv*gv;
  out[hoff+u] = ov*tanhf(c2);
}

extern "C" void kernel_launch(void* const* d_in, const int* in_sizes, int n_in,
                              void* d_out, int out_size, void* d_ws, size_t ws_size,
                              hipStream_t stream)
{
  const float* x   = (const float*)d_in[0];
  const float* h0  = (const float*)d_in[1];
  const float* c0  = (const float*)d_in[2];
  const float* A   = (const float*)d_in[3];
  const float* ei  = (const float*)d_in[4];
  const float* wg0 = (const float*)d_in[5];
  const float* bg0 = (const float*)d_in[6];
  const float* wg1 = (const float*)d_in[7];
  const float* bg1 = (const float*)d_in[8];
  const float* wr1 = (const float*)d_in[9];
  const float* br1 = (const float*)d_in[10];
  const float* kern  = (const float*)d_in[11];
  const float* kernB = (const float*)d_in[12];
  const float* kernW = (const float*)d_in[13];
  const float* rk    = (const float*)d_in[14];
  const float* rkB   = (const float*)d_in[15];
  const float* rkW   = (const float*)d_in[16];
  const float* bias  = (const float*)d_in[17];
  const float* biasB = (const float*)d_in[18];
  const float* biasW = (const float*)d_in[19];
  float* out = (float*)d_out;
  char* wsb  = (char*)d_ws;

  // ws layout (bytes), total 146.6 MB (< 157.3 MB proven):
  //  [0, 52428800)                        featb (bf16, 102400x256)
  //  [52428800, 94158848)                 weights: WbJ 1MB | WbB 13.6MB | WbW 26.7MB | Wc2 256KB | Wc1 48KB
  //  [94158848, 146587648)   dyn region:  graph temps (ycat 39.3MB | y 13.1MB; xcat overlays ycat)
  //                                       then (overlaid) part: split-K partials, 50.3 MB
  unsigned short* featb = (unsigned short*)wsb;
  unsigned short* WbJ = (unsigned short*)(wsb + 52428800);
  unsigned short* WbB = WbJ + 524288;
  unsigned short* WbW = WbB + 6815744;
  unsigned short* Wc2 = WbW + 13369344;
  unsigned short* Wc1 = Wc2 + 131072;
  char* dyn = wsb + 94158848;
  unsigned short* ycat = (unsigned short*)dyn;                  // 51200*384
  unsigned short* xcat = ycat;                                  // 51200*192 (overlay, dead before ycat)
  unsigned short* yb   = (unsigned short*)(dyn + 39321600);     // 51200*128
  float* part = (float*)dyn;                                    // 50331648 B

  // weights -> bf16 fragment order (read-only inputs; independent of dyn)
  kConvW<0><<<(524288+255)/256,   256, 0, stream>>>(kern,  rk,  WbJ, 524288);
  kConvW<1><<<(6815744+255)/256,  256, 0, stream>>>(kernB, rkB, WbB, 6815744);
  kConvW<2><<<(13369344+255)/256, 256, 0, stream>>>(kernW, rkW, WbW, 13369344);
  kConvW<3><<<(131072+255)/256,   256, 0, stream>>>(wg1, wr1, Wc2, 131072);
  kConvW<4><<<(24576+255)/256,    256, 0, stream>>>(wg0, nullptr, Wc1, 24576);

  for(int c=0;c<NCH;++c){
    const float* xc = x + (size_t)c*NnC*(Vv*Dd);
    kMix<64,float>          <<<NnC, 192, 0, stream>>>(xc, A, ei, 0, xcat);
    kGC1<<<RCn/128, 256, 0, stream>>>(xcat, Wc1, bg0, A, ei, yb);
    kMix<128,unsigned short><<<NnC, 384, 0, stream>>>(yb, A, ei, 1875, ycat);
    kGC2<<<RCn/128, 256, 0, stream>>>(ycat, yb, Wc2, bg1, br1, A, ei,
                                      featb + (size_t)c*RCn*256);
  }
  // joint: direct MFMA + fused LSTM epilogue (800x4 = 3200 blocks)
  kLSTMm<0><<<dim3(N3/128,4),   256, 0, stream>>>(featb, h0, c0, WbJ, bias, out, 512);
  // body: split-K S=3 (KC=2240; 2240+2240+2176=6656), 32x4x3 = 384 blocks
  kLSTMm<1><<<dim3(Nn/128,4,3), 256, 0, stream>>>(featb, h0, nullptr, WbB, nullptr, part, 2240);
  kFin<1><<<Nn, 256, 0, stream>>>(part, c0, biasB, out, 3);
  // whole: split-K S=6 (KC=2176; 6*2176=13056), 16x4x6 = 384 blocks
  kLSTMm<2><<<dim3(Bn/128,4,6), 256, 0, stream>>>(featb, h0, nullptr, WbW, nullptr, part, 2176);
  kFin<2><<<Bn, 256, 0, stream>>>(part, c0, biasW, out, 6);
}

// Round 8
// 1065.141 us; speedup vs baseline: 13.7129x; 1.0475x over previous
//
#include <hip/hip_runtime.h>
#include <hip/hip_bf16.h>
#include <math.h>

// Problem constants
constexpr int Bn = 2048, Mm = 2, Vv = 25, Dd = 64;
constexpr int C1 = 128, C2 = 256, Kk = 3, Uu = 256;
constexpr int NJ = Mm*Vv*Uu;     // 12800
constexpr int NBd = Mm*Uu;       // 512
constexpr int SD = NJ+NBd+Uu;    // 13568
constexpr int Nn = Bn*Mm;        // 4096
constexpr int N3 = Nn*Vv;        // 102400
constexpr int NCH = 2;
constexpr int NnC = Nn/NCH;      // 2048
constexpr int RCn = NnC*Vv;      // 51200 rows per chunk

typedef __bf16 v8bf __attribute__((ext_vector_type(8)));
typedef float f32x16 __attribute__((ext_vector_type(16)));

__device__ __forceinline__ float hsig(float z){ return fminf(fmaxf(0.2f*z+0.5f,0.f),1.f); }
__device__ __forceinline__ unsigned short f2bs(float x){
  __hip_bfloat16 h = __float2bfloat16(x);
  unsigned short s; __builtin_memcpy(&s, &h, 2); return s;
}
__device__ __forceinline__ float bs2f(unsigned short s){
  unsigned u = ((unsigned)s)<<16; float f; __builtin_memcpy(&f,&u,4); return f;
}

// ---------------------------------------------------------------------------
// kMix<SW,TI>: v-mixing by adjacency (unchanged, verified)
// ---------------------------------------------------------------------------
template<int SW, typename TI>
__global__ __launch_bounds__(SW*3) void kMix(
    const TI* __restrict__ src, const float* __restrict__ Amat,
    const float* __restrict__ ei, int eoff, unsigned short* __restrict__ dst)
{
  __shared__ float xs[Vv*SW];
  __shared__ float as[Kk*Vv*Vv];
  const int n = blockIdx.x, t = threadIdx.x;
  const TI* srow = src + (size_t)n*(Vv*SW);
  for(int i=t;i<Vv*SW;i+=SW*3){
    if constexpr (sizeof(TI)==2) xs[i]=bs2f((unsigned short)srow[i]);
    else xs[i]=srow[i];
  }
  for(int i=t;i<Kk*Vv*Vv;i+=SW*3) as[i]=ei[eoff+i]*Amat[i];
  __syncthreads();
  const int k = t/SW, d = t%SW;
  float acc[Vv];
  #pragma unroll
  for(int w=0;w<Vv;++w) acc[w]=0.f;
  for(int v=0;v<Vv;++v){
    float xv = xs[v*SW+d];
    const float* ap = &as[k*625 + v*25];
    #pragma unroll
    for(int w=0;w<Vv;++w) acc[w] += ap[w]*xv;
  }
  unsigned short* drow = dst + (size_t)n*(Vv*3*SW);
  for(int w=0;w<Vv;++w) drow[w*(3*SW) + t] = f2bs(acc[w]);
}

// ---------------------------------------------------------------------------
// hoffOf: MODE 0 joint, 1 body, 2 whole
// ---------------------------------------------------------------------------
template<int MODE>
__device__ __forceinline__ size_t hoffOf(int row){
  if constexpr (MODE==0){ int b=row/50, j=row-b*50; return (size_t)b*SD + j*256; }
  else if constexpr (MODE==1){ int b=row>>1, m=row&1; return (size_t)b*SD + NJ + m*256; }
  else return (size_t)row*SD + NJ + NBd;
}

// ---------------------------------------------------------------------------
// kConvW<MODE>: weights fp32 -> bf16 in MFMA FRAGMENT order (unchanged).
// ---------------------------------------------------------------------------
template<int MODE>
__global__ __launch_bounds__(256) void kConvW(
    const float* __restrict__ Wm, const float* __restrict__ Wr,
    unsigned short* __restrict__ out, int total)
{
  int i = blockIdx.x*256 + threadIdx.x;
  if(i>=total) return;
  int e = i&7, ln = (i>>3)&63, l31 = ln&31, l5 = ln>>5;
  float v;
  if constexpr (MODE<=2){
    constexpr int KF = (MODE==0)?256:(MODE==1)?6400:12800;
    constexpr int NKT = (KF+256)/32;
    int fb = (i>>9)&15, kt = (i>>13)%NKT, ublk = i/(NKT*8192);
    int kh = fb&1, cg = fb>>1;
    int k = kt*32 + l5*8 + kh*16 + e;
    int g = cg&3, uu = (cg>>2)*32 + l31;
    int col = g*256 + ublk*64 + uu;
    v = (k<KF) ? Wm[(size_t)k*1024+col] : Wr[(size_t)(k-KF)*1024+col];
  } else if constexpr (MODE==3){
    int fb = (i>>9)&15, kt = i>>13;
    int kh = fb&1, cg = fb>>1;
    int k = kt*32 + l5*8 + kh*16 + e;
    int col = cg*32 + l31;
    v = (k<384) ? Wm[(size_t)(k&127)*768 + (k>>7)*256 + col]
                : Wr[(size_t)(k-384)*256 + col];
  } else {
    int fb = (i>>9)&7, kt = i>>12;
    int kh = fb&1, cg = fb>>1;
    int k = kt*32 + l5*8 + kh*16 + e;
    int col = cg*32 + l31;
    v = Wm[(size_t)(k&63)*384 + (k>>6)*128 + col];
  }
  out[i] = f2bs(v);
}

// ---------------------------------------------------------------------------
// kLSTMm<MODE,MR>: MFMA bf16 GEMM, block tile MR rows x 256 staged cols,
// 4 waves (2 row x 2 col).  MR=64: wave 32x128 (occupancy-priority, short K).
// MR=128: wave 64x128 (LDS-traffic-priority, long K).
// DOUBLE-BUFFERED fragment-linear LDS: one barrier per K-step; stage of
// step s+1 overlaps MFMA of step s.  All ds ops frag*1KB + lane*16B.
// MODE 0: fused LSTM epilogue -> out.  MODE 1/2: split-K partials -> part.
// ---------------------------------------------------------------------------
template<int MODE, int MR>
__global__ __launch_bounds__(256,2) void kLSTMm(
    const unsigned short* __restrict__ featb, const float* __restrict__ h0,
    const float* __restrict__ c0, const unsigned short* __restrict__ Wcat,
    const float* __restrict__ bias, float* __restrict__ outp, int KC)
{
  constexpr int KF = (MODE==0)?256:(MODE==1)?6400:12800;
  constexpr int KT = KF+256;
  constexpr int NKT = KT/32;
  constexpr int ROWS = (MODE==0)?N3:(MODE==1)?Nn:Bn;
  constexpr int NRG = MR/64;            // rowgroups per wave (and uint4/thread for A)
  constexpr int NAF = (MR/32)*2;        // A frags per buffer
  __shared__ unsigned short Afr[2][NAF*512];
  __shared__ unsigned short Bfr[2][16*512];
  const int t = threadIdx.x;
  const int r0 = blockIdx.x*MR;
  const int ublk = blockIdx.y;
  const int z = (MODE==0)?0:blockIdx.z;
  const int kBeg = z*KC, kEnd = min(KT, kBeg+KC);
  const int lane = t&63, wid = t>>6;
  const int wr = wid>>1, w2 = wid&1;
  const int l31 = lane&31, l5 = lane>>5;

  f32x16 acc[NRG][4];
  #pragma unroll
  for(int rg=0;rg<NRG;++rg)
    #pragma unroll
    for(int g=0;g<4;++g)
      #pragma unroll
      for(int j=0;j<16;++j) acc[rg][g][j]=0.f;

  auto stageA = [&](unsigned short* dst, int k0){
    #pragma unroll
    for(int i=0;i<NRG;++i){
      int fi = i*256 + t;                      // [rgg][kh][ln]
      int ln = fi&63;
      int row = r0 + (fi>>7)*32 + (ln&31);
      int kc = (ln>>5) + ((fi>>6)&1)*2;
      int kg = k0 + kc*8;
      uint4 av;
      if(kg < KF){
        av = *(const uint4*)(featb + (size_t)row*KF + kg);
      } else {
        const float* hs = h0 + hoffOf<MODE>(row) + (kg - KF);
        float4 f0 = *(const float4*)hs;
        float4 f1 = *(const float4*)(hs+4);
        av.x = (unsigned)f2bs(f0.x) | ((unsigned)f2bs(f0.y)<<16);
        av.y = (unsigned)f2bs(f0.z) | ((unsigned)f2bs(f0.w)<<16);
        av.z = (unsigned)f2bs(f1.x) | ((unsigned)f2bs(f1.y)<<16);
        av.w = (unsigned)f2bs(f1.z) | ((unsigned)f2bs(f1.w)<<16);
      }
      *(uint4*)&dst[fi*8] = av;
    }
  };
  auto stageB = [&](unsigned short* dst, int k0){
    const unsigned short* wt = Wcat + ((size_t)ublk*NKT + (k0>>5))*8192;
    #pragma unroll
    for(int i=0;i<4;++i){
      int fi = i*256 + t;
      *(uint4*)&dst[fi*8] = *(const uint4*)(wt + fi*8);
    }
  };

  stageA(Afr[0], kBeg); stageB(Bfr[0], kBeg);
  __syncthreads();
  const int nst = (kEnd-kBeg)>>5;
  for(int s=0; s<nst; ++s){
    const int cur = s&1;
    if(s+1<nst){ stageA(Afr[cur^1], kBeg+(s+1)*32); stageB(Bfr[cur^1], kBeg+(s+1)*32); }
    #pragma unroll
    for(int kh=0; kh<2; ++kh){
      v8bf a[NRG];
      #pragma unroll
      for(int rg=0;rg<NRG;++rg)
        a[rg] = *(const v8bf*)&Afr[cur][((wr*NRG+rg)*2+kh)*512 + lane*8];
      #pragma unroll
      for(int g=0; g<4; ++g){
        v8bf b = *(const v8bf*)&Bfr[cur][((w2*4+g)*2+kh)*512 + lane*8];
        #pragma unroll
        for(int rg=0;rg<NRG;++rg)
          acc[rg][g] = __builtin_amdgcn_mfma_f32_32x32x16_bf16(a[rg], b, acc[rg][g], 0, 0, 0);
      }
    }
    __syncthreads();
  }

  const int u = ublk*64 + w2*32 + l31;
  if constexpr (MODE==0){
    #pragma unroll
    for(int rg=0;rg<NRG;++rg){
      #pragma unroll
      for(int reg=0; reg<16; ++reg){
        int row = r0 + (wr*NRG+rg)*32 + (reg&3) + 8*(reg>>2) + 4*l5;
        int b = row/50, j = row - b*50;
        size_t hoff = (size_t)b*SD + j*256;
        int boff = j*1024;
        float zi = acc[rg][0][reg] + bias[boff + u];
        float zf = acc[rg][1][reg] + bias[boff + 256 + u];
        float zg = acc[rg][2][reg] + bias[boff + 512 + u];
        float zo = acc[rg][3][reg] + bias[boff + 768 + u];
        float iv=hsig(zi), fv=hsig(zf), gv=tanhf(zg), ov=hsig(zo);
        float cc = c0[hoff+u];
        float c2 = fv*cc + iv*gv;
        outp[hoff+u] = ov*tanhf(c2);
      }
    }
  } else {
    #pragma unroll
    for(int rg=0;rg<NRG;++rg){
      #pragma unroll
      for(int reg=0; reg<16; ++reg){
        int row = r0 + (wr*NRG+rg)*32 + (reg&3) + 8*(reg>>2) + 4*l5;
        float* base = outp + ((size_t)z*ROWS + row)*1024 + u;
        base[0]   = acc[rg][0][reg];
        base[256] = acc[rg][1][reg];
        base[512] = acc[rg][2][reg];
        base[768] = acc[rg][3][reg];
      }
    }
  }
}

// ---------------------------------------------------------------------------
// kGC2: graph GEMM2, MFMA, 64x256 tile, double-buffered (wave 32x128).
// feat = relu([ycat|y] @ Wc2 + bias1(w,c)), bf16 out.
// ---------------------------------------------------------------------------
__global__ __launch_bounds__(256,2) void kGC2(
    const unsigned short* __restrict__ ycat, const unsigned short* __restrict__ yb,
    const unsigned short* __restrict__ Wc2, const float* __restrict__ bg1,
    const float* __restrict__ br1, const float* __restrict__ Amat,
    const float* __restrict__ ei, unsigned short* __restrict__ featb)
{
  __shared__ unsigned short Afr[2][4*512];
  __shared__ unsigned short Bfr[2][16*512];
  __shared__ float asums[75];
  const int t = threadIdx.x;
  const int r0 = blockIdx.x*64;
  if(t<75){
    int k=t/25, w=t%25; float s=0.f;
    for(int v=0;v<25;++v) s += ei[1875 + k*625+v*25+w]*Amat[k*625+v*25+w];
    asums[t]=s;
  }
  const int lane = t&63, wid = t>>6;
  const int wr = wid>>1, w2 = wid&1;
  const int l31 = lane&31, l5 = lane>>5;
  f32x16 acc[4];
  #pragma unroll
  for(int g=0;g<4;++g)
    #pragma unroll
    for(int j=0;j<16;++j) acc[g][j]=0.f;

  auto stageA = [&](unsigned short* dst, int k0){
    int fi = t, ln = fi&63;
    int row = r0 + (fi>>7)*32 + (ln&31);
    int kc = (ln>>5) + ((fi>>6)&1)*2;
    int kg = k0 + kc*8;
    uint4 av = (kg<384) ? *(const uint4*)(ycat + (size_t)row*384 + kg)
                        : *(const uint4*)(yb   + (size_t)row*128 + (kg-384));
    *(uint4*)&dst[fi*8] = av;
  };
  auto stageB = [&](unsigned short* dst, int k0){
    const unsigned short* wt = Wc2 + (size_t)(k0>>5)*8192;
    #pragma unroll
    for(int i=0;i<4;++i){
      int fi = i*256 + t;
      *(uint4*)&dst[fi*8] = *(const uint4*)(wt + fi*8);
    }
  };

  stageA(Afr[0],0); stageB(Bfr[0],0);
  __syncthreads();
  for(int s=0; s<16; ++s){
    const int cur = s&1;
    if(s+1<16){ stageA(Afr[cur^1],(s+1)*32); stageB(Bfr[cur^1],(s+1)*32); }
    #pragma unroll
    for(int kh=0; kh<2; ++kh){
      v8bf a = *(const v8bf*)&Afr[cur][(wr*2+kh)*512 + lane*8];
      #pragma unroll
      for(int g=0; g<4; ++g){
        v8bf b = *(const v8bf*)&Bfr[cur][((w2*4+g)*2+kh)*512 + lane*8];
        acc[g] = __builtin_amdgcn_mfma_f32_32x32x16_bf16(a, b, acc[g], 0, 0, 0);
      }
    }
    __syncthreads();
  }
  #pragma unroll
  for(int reg=0; reg<16; ++reg){
    int row = r0 + wr*32 + (reg&3) + 8*(reg>>2) + 4*l5;
    int w = row % 25;
    float a0w = asums[w], a1w = asums[25+w], a2w = asums[50+w];
    #pragma unroll
    for(int g=0; g<4; ++g){
      int cc = w2*128 + g*32 + l31;
      float b = br1[cc] + a0w*bg1[cc] + a1w*bg1[256+cc] + a2w*bg1[512+cc];
      featb[(size_t)row*256 + cc] = f2bs(fmaxf(acc[g][reg] + b, 0.f));
    }
  }
}

// ---------------------------------------------------------------------------
// kGC1: graph GEMM1, MFMA, 64x128 tile, double-buffered (wave 32x64).
// y = relu(xcat @ Wc1 + bias0(w,c)), bf16 out.
// ---------------------------------------------------------------------------
__global__ __launch_bounds__(256,2) void kGC1(
    const unsigned short* __restrict__ xcat, const unsigned short* __restrict__ Wc1,
    const float* __restrict__ bg0, const float* __restrict__ Amat,
    const float* __restrict__ ei, unsigned short* __restrict__ yb)
{
  __shared__ unsigned short Afr[2][4*512];
  __shared__ unsigned short Bfr[2][8*512];
  __shared__ float asums[75];
  const int t = threadIdx.x;
  const int r0 = blockIdx.x*64;
  if(t<75){
    int k=t/25, w=t%25; float s=0.f;
    for(int v=0;v<25;++v) s += ei[k*625+v*25+w]*Amat[k*625+v*25+w];
    asums[t]=s;
  }
  const int lane = t&63, wid = t>>6;
  const int wr = wid>>1, w2 = wid&1;
  const int l31 = lane&31, l5 = lane>>5;
  f32x16 acc[2];
  #pragma unroll
  for(int g=0;g<2;++g)
    #pragma unroll
    for(int j=0;j<16;++j) acc[g][j]=0.f;

  auto stageA = [&](unsigned short* dst, int k0){
    int fi = t, ln = fi&63;
    int row = r0 + (fi>>7)*32 + (ln&31);
    int kc = (ln>>5) + ((fi>>6)&1)*2;
    int kg = k0 + kc*8;
    *(uint4*)&dst[fi*8] = *(const uint4*)(xcat + (size_t)row*192 + kg);
  };
  auto stageB = [&](unsigned short* dst, int k0){
    const unsigned short* wt = Wc1 + (size_t)(k0>>5)*4096;
    #pragma unroll
    for(int i=0;i<2;++i){
      int fi = i*256 + t;
      *(uint4*)&dst[fi*8] = *(const uint4*)(wt + fi*8);
    }
  };

  stageA(Afr[0],0); stageB(Bfr[0],0);
  __syncthreads();
  for(int s=0; s<6; ++s){
    const int cur = s&1;
    if(s+1<6){ stageA(Afr[cur^1],(s+1)*32); stageB(Bfr[cur^1],(s+1)*32); }
    #pragma unroll
    for(int kh=0; kh<2; ++kh){
      v8bf a = *(const v8bf*)&Afr[cur][(wr*2+kh)*512 + lane*8];
      #pragma unroll
      for(int g=0; g<2; ++g){
        v8bf b = *(const v8bf*)&Bfr[cur][((w2*2+g)*2+kh)*512 + lane*8];
        acc[g] = __builtin_amdgcn_mfma_f32_32x32x16_bf16(a, b, acc[g], 0, 0, 0);
      }
    }
    __syncthreads();
  }
  #pragma unroll
  for(int reg=0; reg<16; ++reg){
    int row = r0 + wr*32 + (reg&3) + 8*(reg>>2) + 4*l5;
    int w = row % 25;
    float a0w = asums[w], a1w = asums[25+w], a2w = asums[50+w];
    #pragma unroll
    for(int g=0; g<2; ++g){
      int cc = w2*64 + g*32 + l31;
      float b = a0w*bg0[cc] + a1w*bg0[128+cc] + a2w*bg0[256+cc];
      yb[(size_t)row*128 + cc] = f2bs(fmaxf(acc[g][reg] + b, 0.f));
    }
  }
}

// ---------------------------------------------------------------------------
// kFin<MODE>: sum S partials + bias, LSTM pointwise (unchanged, verified)
// ---------------------------------------------------------------------------
template<int MODE>
__global__ __launch_bounds__(256) void kFin(
    const float* __restrict__ part, const float* __restrict__ c0,
    const float* __restrict__ bias, float* __restrict__ out, int S)
{
  constexpr int ROWS = (MODE==1)?Nn:Bn;
  const int row = blockIdx.x, u = threadIdx.x;
  size_t hoff = hoffOf<MODE>(row);
  int boff = (MODE==1)?((row&1)*1024):0;
  float zg4[4] = { bias[boff+u], bias[boff+256+u], bias[boff+512+u], bias[boff+768+u] };
  for(int s=0;s<S;++s){
    const float* p = part + ((size_t)s*ROWS + row)*1024;
    #pragma unroll
    for(int g=0;g<4;++g) zg4[g] += p[g*256+u];
  }
  float iv=hsig(zg4[0]), fv=hsig(zg4[1]), gv=tanhf(zg4[2]), ov=hsig(zg4[3]);
  float cc = c0[hoff+u];
  float c2 = fv*cc + iv*gv;
  out[hoff+u] = ov*tanhf(c2);
}

extern "C" void kernel_launch(void* const* d_in, const int* in_sizes, int n_in,
                              void* d_out, int out_size, void* d_ws, size_t ws_size,
                              hipStream_t stream)
{
  const float* x   = (const float*)d_in[0];
  const float* h0  = (const float*)d_in[1];
  const float* c0  = (const float*)d_in[2];
  const float* A   = (const float*)d_in[3];
  const float* ei  = (const float*)d_in[4];
  const float* wg0 = (const float*)d_in[5];
  const float* bg0 = (const float*)d_in[6];
  const float* wg1 = (const float*)d_in[7];
  const float* bg1 = (const float*)d_in[8];
  const float* wr1 = (const float*)d_in[9];
  const float* br1 = (const float*)d_in[10];
  const float* kern  = (const float*)d_in[11];
  const float* kernB = (const float*)d_in[12];
  const float* kernW = (const float*)d_in[13];
  const float* rk    = (const float*)d_in[14];
  const float* rkB   = (const float*)d_in[15];
  const float* rkW   = (const float*)d_in[16];
  const float* bias  = (const float*)d_in[17];
  const float* biasB = (const float*)d_in[18];
  const float* biasW = (const float*)d_in[19];
  float* out = (float*)d_out;
  char* wsb  = (char*)d_ws;

  // ws layout (bytes), total 146.6 MB (< 157.3 MB proven):
  //  [0, 52428800)                        featb (bf16, 102400x256)
  //  [52428800, 94158848)                 weights: WbJ 1MB | WbB 13.6MB | WbW 26.7MB | Wc2 256KB | Wc1 48KB
  //  [94158848, 146587648)   dyn region:  graph temps (ycat 39.3MB | y 13.1MB; xcat overlays ycat)
  //                                       then (overlaid) part: split-K partials, 50.3 MB
  unsigned short* featb = (unsigned short*)wsb;
  unsigned short* WbJ = (unsigned short*)(wsb + 52428800);
  unsigned short* WbB = WbJ + 524288;
  unsigned short* WbW = WbB + 6815744;
  unsigned short* Wc2 = WbW + 13369344;
  unsigned short* Wc1 = Wc2 + 131072;
  char* dyn = wsb + 94158848;
  unsigned short* ycat = (unsigned short*)dyn;                  // 51200*384
  unsigned short* xcat = ycat;                                  // 51200*192 (overlay, dead before ycat)
  unsigned short* yb   = (unsigned short*)(dyn + 39321600);     // 51200*128
  float* part = (float*)dyn;                                    // 50331648 B

  // weights -> bf16 fragment order
  kConvW<0><<<(524288+255)/256,   256, 0, stream>>>(kern,  rk,  WbJ, 524288);
  kConvW<1><<<(6815744+255)/256,  256, 0, stream>>>(kernB, rkB, WbB, 6815744);
  kConvW<2><<<(13369344+255)/256, 256, 0, stream>>>(kernW, rkW, WbW, 13369344);
  kConvW<3><<<(131072+255)/256,   256, 0, stream>>>(wg1, wr1, Wc2, 131072);
  kConvW<4><<<(24576+255)/256,    256, 0, stream>>>(wg0, nullptr, Wc1, 24576);

  for(int c=0;c<NCH;++c){
    const float* xc = x + (size_t)c*NnC*(Vv*Dd);
    kMix<64,float>          <<<NnC, 192, 0, stream>>>(xc, A, ei, 0, xcat);
    kGC1<<<RCn/64, 256, 0, stream>>>(xcat, Wc1, bg0, A, ei, yb);
    kMix<128,unsigned short><<<NnC, 384, 0, stream>>>(yb, A, ei, 1875, ycat);
    kGC2<<<RCn/64, 256, 0, stream>>>(ycat, yb, Wc2, bg1, br1, A, ei,
                                     featb + (size_t)c*RCn*256);
  }
  // joint: 64-row tile (occupancy) + dbuf, 1600x4 = 6400 blocks
  kLSTMm<0,64><<<dim3(N3/64,4),    256, 0, stream>>>(featb, h0, c0, WbJ, bias, out, 512);
  // body: split-K S=3 (KC=2240), 128-row tile, 32x4x3 = 384 blocks
  kLSTMm<1,128><<<dim3(Nn/128,4,3), 256, 0, stream>>>(featb, h0, nullptr, WbB, nullptr, part, 2240);
  kFin<1><<<Nn, 256, 0, stream>>>(part, c0, biasB, out, 3);
  // whole: split-K S=6 (KC=2176), 16x4x6 = 384 blocks
  kLSTMm<2,128><<<dim3(Bn/128,4,6), 256, 0, stream>>>(featb, h0, nullptr, WbW, nullptr, part, 2176);
  kFin<2><<<Bn, 256, 0, stream>>>(part, c0, biasW, out, 6);
}

// Round 11
// 746.253 us; speedup vs baseline: 19.5727x; 1.4273x over previous
//
#include <hip/hip_runtime.h>
#include <hip/hip_bf16.h>
#include <math.h>

// Problem constants
constexpr int Bn = 2048, Mm = 2, Vv = 25, Dd = 64;
constexpr int C1 = 128, C2 = 256, Kk = 3, Uu = 256;
constexpr int NJ = Mm*Vv*Uu;     // 12800
constexpr int NBd = Mm*Uu;       // 512
constexpr int SD = NJ+NBd+Uu;    // 13568
constexpr int Nn = Bn*Mm;        // 4096
constexpr int N3 = Nn*Vv;        // 102400
constexpr int NCH = 2;
constexpr int NnC = Nn/NCH;      // 2048
constexpr int RCn = NnC*Vv;      // 51200 rows per chunk

typedef __bf16 v8bf __attribute__((ext_vector_type(8)));
typedef float f32x16 __attribute__((ext_vector_type(16)));

__device__ __forceinline__ float hsig(float z){ return fminf(fmaxf(0.2f*z+0.5f,0.f),1.f); }
__device__ __forceinline__ float ftanh(float x){
  float e = __expf(2.f*x);
  return 1.f - 2.f*__frcp_rn(e+1.f);
}
__device__ __forceinline__ unsigned short f2bs(float x){
  __hip_bfloat16 h = __float2bfloat16(x);
  unsigned short s; __builtin_memcpy(&s, &h, 2); return s;
}
__device__ __forceinline__ float bs2f(unsigned short s){
  unsigned u = ((unsigned)s)<<16; float f; __builtin_memcpy(&f,&u,4); return f;
}

// Async global->LDS 16B: dst_base is the wave-uniform frag base; HW writes
// base + lane*16.  Fallback path does the same through VGPRs.
#if defined(__has_builtin)
#if __has_builtin(__builtin_amdgcn_global_load_lds)
#define HAS_ALD 1
#endif
#endif
#ifndef HAS_ALD
#define HAS_ALD 0
#endif
__device__ __forceinline__ void stage16(unsigned short* dst_base, int lane, const void* src){
#if HAS_ALD
  __builtin_amdgcn_global_load_lds(
      (const __attribute__((address_space(1))) unsigned int*)src,
      (__attribute__((address_space(3))) unsigned int*)dst_base, 16, 0, 0);
#else
  *(uint4*)(dst_base + lane*8) = *(const uint4*)src;
#endif
}

// ---------------------------------------------------------------------------
// kMix<SW,TI>: v-mixing by adjacency (unchanged, verified)
// ---------------------------------------------------------------------------
template<int SW, typename TI>
__global__ __launch_bounds__(SW*3) void kMix(
    const TI* __restrict__ src, const float* __restrict__ Amat,
    const float* __restrict__ ei, int eoff, unsigned short* __restrict__ dst)
{
  __shared__ float xs[Vv*SW];
  __shared__ float as[Kk*Vv*Vv];
  const int n = blockIdx.x, t = threadIdx.x;
  const TI* srow = src + (size_t)n*(Vv*SW);
  for(int i=t;i<Vv*SW;i+=SW*3){
    if constexpr (sizeof(TI)==2) xs[i]=bs2f((unsigned short)srow[i]);
    else xs[i]=srow[i];
  }
  for(int i=t;i<Kk*Vv*Vv;i+=SW*3) as[i]=ei[eoff+i]*Amat[i];
  __syncthreads();
  const int k = t/SW, d = t%SW;
  float acc[Vv];
  #pragma unroll
  for(int w=0;w<Vv;++w) acc[w]=0.f;
  for(int v=0;v<Vv;++v){
    float xv = xs[v*SW+d];
    const float* ap = &as[k*625 + v*25];
    #pragma unroll
    for(int w=0;w<Vv;++w) acc[w] += ap[w]*xv;
  }
  unsigned short* drow = dst + (size_t)n*(Vv*3*SW);
  for(int w=0;w<Vv;++w) drow[w*(3*SW) + t] = f2bs(acc[w]);
}

// ---------------------------------------------------------------------------
// hoffOf: MODE 0 joint, 1 body, 2 whole
// ---------------------------------------------------------------------------
template<int MODE>
__device__ __forceinline__ size_t hoffOf(int row){
  if constexpr (MODE==0){ int b=row/50, j=row-b*50; return (size_t)b*SD + j*256; }
  else if constexpr (MODE==1){ int b=row>>1, m=row&1; return (size_t)b*SD + NJ + m*256; }
  else return (size_t)row*SD + NJ + NBd;
}

// ---------------------------------------------------------------------------
// kConvW<MODE>: weights fp32 -> bf16 in MFMA FRAGMENT order (unchanged).
// ---------------------------------------------------------------------------
template<int MODE>
__global__ __launch_bounds__(256) void kConvW(
    const float* __restrict__ Wm, const float* __restrict__ Wr,
    unsigned short* __restrict__ out, int total)
{
  int i = blockIdx.x*256 + threadIdx.x;
  if(i>=total) return;
  int e = i&7, ln = (i>>3)&63, l31 = ln&31, l5 = ln>>5;
  float v;
  if constexpr (MODE<=2){
    constexpr int KF = (MODE==0)?256:(MODE==1)?6400:12800;
    constexpr int NKT = (KF+256)/32;
    int fb = (i>>9)&15, kt = (i>>13)%NKT, ublk = i/(NKT*8192);
    int kh = fb&1, cg = fb>>1;
    int k = kt*32 + l5*8 + kh*16 + e;
    int g = cg&3, uu = (cg>>2)*32 + l31;
    int col = g*256 + ublk*64 + uu;
    v = (k<KF) ? Wm[(size_t)k*1024+col] : Wr[(size_t)(k-KF)*1024+col];
  } else if constexpr (MODE==3){
    int fb = (i>>9)&15, kt = i>>13;
    int kh = fb&1, cg = fb>>1;
    int k = kt*32 + l5*8 + kh*16 + e;
    int col = cg*32 + l31;
    v = (k<384) ? Wm[(size_t)(k&127)*768 + (k>>7)*256 + col]
                : Wr[(size_t)(k-384)*256 + col];
  } else {
    int fb = (i>>9)&7, kt = i>>12;
    int kh = fb&1, cg = fb>>1;
    int k = kt*32 + l5*8 + kh*16 + e;
    int col = cg*32 + l31;
    v = Wm[(size_t)(k&63)*384 + (k>>6)*128 + col];
  }
  out[i] = f2bs(v);
}

// ---------------------------------------------------------------------------
// kConvH<MODE>: h0 fp32 -> bf16, row-major [rows][256] in GEMM row order.
// MODE0 -> h0bJ (102400 rows), MODE1 -> hB (4096), MODE2 -> hW (2048).
// ---------------------------------------------------------------------------
template<int MODE>
__global__ __launch_bounds__(256) void kConvH(
    const float* __restrict__ h0, unsigned short* __restrict__ dst, int total4)
{
  int i = blockIdx.x*256 + threadIdx.x;
  if(i>=total4) return;
  int row = i>>6, k4 = (i&63)*4;
  const float* s = h0 + hoffOf<MODE>(row) + k4;
  float4 f = *(const float4*)s;
  uint2 o;
  o.x = (unsigned)f2bs(f.x) | ((unsigned)f2bs(f.y)<<16);
  o.y = (unsigned)f2bs(f.z) | ((unsigned)f2bs(f.w)<<16);
  *(uint2*)(dst + (size_t)i*4) = o;
}

// ---------------------------------------------------------------------------
// kLSTMm<MODE,MR>: MFMA bf16 GEMM, block tile MR rows x 256 staged cols,
// 4 waves (2 row x 2 col).  Double-buffered fragment-linear LDS with ASYNC
// global_load_lds staging (pure copies: featb bf16 | h0b bf16 pre-converted).
// Grid: x = rowblocks*4 with ublk INNER (L3 reuse of A rows); y = split-K z.
// MODE 0: fused LSTM epilogue -> out.  MODE 1/2: split-K partials -> part.
// ---------------------------------------------------------------------------
template<int MODE, int MR>
__global__ __launch_bounds__(256,2) void kLSTMm(
    const unsigned short* __restrict__ featb, const unsigned short* __restrict__ h0b,
    const float* __restrict__ c0, const unsigned short* __restrict__ Wcat,
    const float* __restrict__ bias, float* __restrict__ outp, int KC)
{
  constexpr int KF = (MODE==0)?256:(MODE==1)?6400:12800;
  constexpr int KT = KF+256;
  constexpr int NKT = KT/32;
  constexpr int ROWS = (MODE==0)?N3:(MODE==1)?Nn:Bn;
  constexpr int NRG = MR/64;            // uint4 chunks/thread for A, rowgroups/wave
  constexpr int NAF = (MR/32)*2;        // A frags per buffer
  __shared__ unsigned short Afr[2][NAF*512];
  __shared__ unsigned short Bfr[2][16*512];
  const int t = threadIdx.x;
  const int bx = blockIdx.x;
  const int r0 = (bx>>2)*MR;
  const int ublk = bx&3;
  const int z = (MODE==0)?0:blockIdx.y;
  const int kBeg = z*KC, kEnd = min(KT, kBeg+KC);
  const int lane = t&63, wid = t>>6;
  const int wr = wid>>1, w2 = wid&1;
  const int l31 = lane&31, l5 = lane>>5;

  f32x16 acc[NRG][4];
  #pragma unroll
  for(int rg=0;rg<NRG;++rg)
    #pragma unroll
    for(int g=0;g<4;++g)
      #pragma unroll
      for(int j=0;j<16;++j) acc[rg][g][j]=0.f;

  auto stageA = [&](unsigned short* dstb, int k0){
    #pragma unroll
    for(int i=0;i<NRG;++i){
      int fi = i*256 + t;
      int row = r0 + (fi>>7)*32 + l31;
      int kc = (lane>>5) + ((fi>>6)&1)*2;
      int kg = k0 + kc*8;
      const unsigned short* src = (kg < KF)
          ? featb + (size_t)row*KF + kg
          : h0b   + (size_t)row*256 + (kg - KF);
      stage16(dstb + (size_t)(i*256 + wid*64)*8, lane, src);
    }
  };
  auto stageB = [&](unsigned short* dstb, int k0){
    const unsigned short* wt = Wcat + ((size_t)ublk*NKT + (k0>>5))*8192;
    #pragma unroll
    for(int i=0;i<4;++i){
      int fi = i*256 + t;
      stage16(dstb + (size_t)(i*256 + wid*64)*8, lane, wt + (size_t)fi*8);
    }
  };

  stageA(Afr[0], kBeg); stageB(Bfr[0], kBeg);
  __syncthreads();
  const int nst = (kEnd-kBeg)>>5;
  for(int s=0; s<nst; ++s){
    const int cur = s&1;
    if(s+1<nst){ stageA(Afr[cur^1], kBeg+(s+1)*32); stageB(Bfr[cur^1], kBeg+(s+1)*32); }
    #pragma unroll
    for(int kh=0; kh<2; ++kh){
      v8bf a[NRG];
      #pragma unroll
      for(int rg=0;rg<NRG;++rg)
        a[rg] = *(const v8bf*)&Afr[cur][((wr*NRG+rg)*2+kh)*512 + lane*8];
      #pragma unroll
      for(int g=0; g<4; ++g){
        v8bf b = *(const v8bf*)&Bfr[cur][((w2*4+g)*2+kh)*512 + lane*8];
        #pragma unroll
        for(int rg=0;rg<NRG;++rg)
          acc[rg][g] = __builtin_amdgcn_mfma_f32_32x32x16_bf16(a[rg], b, acc[rg][g], 0, 0, 0);
      }
    }
    __syncthreads();
  }

  const int u = ublk*64 + w2*32 + l31;
  if constexpr (MODE==0){
    #pragma unroll
    for(int rg=0;rg<NRG;++rg){
      #pragma unroll
      for(int reg=0; reg<16; ++reg){
        int row = r0 + (wr*NRG+rg)*32 + (reg&3) + 8*(reg>>2) + 4*l5;
        int b = row/50, j = row - b*50;
        size_t hoff = (size_t)b*SD + j*256;
        int boff = j*1024;
        float zi = acc[rg][0][reg] + bias[boff + u];
        float zf = acc[rg][1][reg] + bias[boff + 256 + u];
        float zg = acc[rg][2][reg] + bias[boff + 512 + u];
        float zo = acc[rg][3][reg] + bias[boff + 768 + u];
        float iv=hsig(zi), fv=hsig(zf), gv=ftanh(zg), ov=hsig(zo);
        float cc = c0[hoff+u];
        float c2 = fv*cc + iv*gv;
        outp[hoff+u] = ov*ftanh(c2);
      }
    }
  } else {
    #pragma unroll
    for(int rg=0;rg<NRG;++rg){
      #pragma unroll
      for(int reg=0; reg<16; ++reg){
        int row = r0 + (wr*NRG+rg)*32 + (reg&3) + 8*(reg>>2) + 4*l5;
        float* base = outp + ((size_t)z*ROWS + row)*1024 + u;
        base[0]   = acc[rg][0][reg];
        base[256] = acc[rg][1][reg];
        base[512] = acc[rg][2][reg];
        base[768] = acc[rg][3][reg];
      }
    }
  }
}

// ---------------------------------------------------------------------------
// kGC2: graph GEMM2, MFMA, 64x256 tile, dbuf + async staging.
// feat = relu([ycat|y] @ Wc2 + bias1(w,c)), bf16 out.
// ---------------------------------------------------------------------------
__global__ __launch_bounds__(256,2) void kGC2(
    const unsigned short* __restrict__ ycat, const unsigned short* __restrict__ yb,
    const unsigned short* __restrict__ Wc2, const float* __restrict__ bg1,
    const float* __restrict__ br1, const float* __restrict__ Amat,
    const float* __restrict__ ei, unsigned short* __restrict__ featb)
{
  __shared__ unsigned short Afr[2][4*512];
  __shared__ unsigned short Bfr[2][16*512];
  __shared__ float asums[75];
  const int t = threadIdx.x;
  const int r0 = blockIdx.x*64;
  if(t<75){
    int k=t/25, w=t%25; float s=0.f;
    for(int v=0;v<25;++v) s += ei[1875 + k*625+v*25+w]*Amat[k*625+v*25+w];
    asums[t]=s;
  }
  const int lane = t&63, wid = t>>6;
  const int wr = wid>>1, w2 = wid&1;
  const int l31 = lane&31, l5 = lane>>5;
  f32x16 acc[4];
  #pragma unroll
  for(int g=0;g<4;++g)
    #pragma unroll
    for(int j=0;j<16;++j) acc[g][j]=0.f;

  auto stageA = [&](unsigned short* dst, int k0){
    int fi = t;
    int row = r0 + (fi>>7)*32 + l31;
    int kc = (lane>>5) + ((fi>>6)&1)*2;
    int kg = k0 + kc*8;
    const unsigned short* src = (kg<384) ? ycat + (size_t)row*384 + kg
                                         : yb   + (size_t)row*128 + (kg-384);
    stage16(dst + (size_t)(wid*64)*8, lane, src);
  };
  auto stageB = [&](unsigned short* dst, int k0){
    const unsigned short* wt = Wc2 + (size_t)(k0>>5)*8192;
    #pragma unroll
    for(int i=0;i<4;++i){
      int fi = i*256 + t;
      stage16(dst + (size_t)(i*256 + wid*64)*8, lane, wt + (size_t)fi*8);
    }
  };

  stageA(Afr[0],0); stageB(Bfr[0],0);
  __syncthreads();
  for(int s=0; s<16; ++s){
    const int cur = s&1;
    if(s+1<16){ stageA(Afr[cur^1],(s+1)*32); stageB(Bfr[cur^1],(s+1)*32); }
    #pragma unroll
    for(int kh=0; kh<2; ++kh){
      v8bf a = *(const v8bf*)&Afr[cur][(wr*2+kh)*512 + lane*8];
      #pragma unroll
      for(int g=0; g<4; ++g){
        v8bf b = *(const v8bf*)&Bfr[cur][((w2*4+g)*2+kh)*512 + lane*8];
        acc[g] = __builtin_amdgcn_mfma_f32_32x32x16_bf16(a, b, acc[g], 0, 0, 0);
      }
    }
    __syncthreads();
  }
  #pragma unroll
  for(int reg=0; reg<16; ++reg){
    int row = r0 + wr*32 + (reg&3) + 8*(reg>>2) + 4*l5;
    int w = row % 25;
    float a0w = asums[w], a1w = asums[25+w], a2w = asums[50+w];
    #pragma unroll
    for(int g=0; g<4; ++g){
      int cc = w2*128 + g*32 + l31;
      float b = br1[cc] + a0w*bg1[cc] + a1w*bg1[256+cc] + a2w*bg1[512+cc];
      featb[(size_t)row*256 + cc] = f2bs(fmaxf(acc[g][reg] + b, 0.f));
    }
  }
}

// ---------------------------------------------------------------------------
// kGC1: graph GEMM1, MFMA, 64x128 tile, dbuf + async staging.
// y = relu(xcat @ Wc1 + bias0(w,c)), bf16 out.
// ---------------------------------------------------------------------------
__global__ __launch_bounds__(256,2) void kGC1(
    const unsigned short* __restrict__ xcat, const unsigned short* __restrict__ Wc1,
    const float* __restrict__ bg0, const float* __restrict__ Amat,
    const float* __restrict__ ei, unsigned short* __restrict__ yb)
{
  __shared__ unsigned short Afr[2][4*512];
  __shared__ unsigned short Bfr[2][8*512];
  __shared__ float asums[75];
  const int t = threadIdx.x;
  const int r0 = blockIdx.x*64;
  if(t<75){
    int k=t/25, w=t%25; float s=0.f;
    for(int v=0;v<25;++v) s += ei[k*625+v*25+w]*Amat[k*625+v*25+w];
    asums[t]=s;
  }
  const int lane = t&63, wid = t>>6;
  const int wr = wid>>1, w2 = wid&1;
  const int l31 = lane&31, l5 = lane>>5;
  f32x16 acc[2];
  #pragma unroll
  for(int g=0;g<2;++g)
    #pragma unroll
    for(int j=0;j<16;++j) acc[g][j]=0.f;

  auto stageA = [&](unsigned short* dst, int k0){
    int fi = t;
    int row = r0 + (fi>>7)*32 + l31;
    int kc = (lane>>5) + ((fi>>6)&1)*2;
    int kg = k0 + kc*8;
    stage16(dst + (size_t)(wid*64)*8, lane, xcat + (size_t)row*192 + kg);
  };
  auto stageB = [&](unsigned short* dst, int k0){
    const unsigned short* wt = Wc1 + (size_t)(k0>>5)*4096;
    #pragma unroll
    for(int i=0;i<2;++i){
      int fi = i*256 + t;
      stage16(dst + (size_t)(i*256 + wid*64)*8, lane, wt + (size_t)fi*8);
    }
  };

  stageA(Afr[0],0); stageB(Bfr[0],0);
  __syncthreads();
  for(int s=0; s<6; ++s){
    const int cur = s&1;
    if(s+1<6){ stageA(Afr[cur^1],(s+1)*32); stageB(Bfr[cur^1],(s+1)*32); }
    #pragma unroll
    for(int kh=0; kh<2; ++kh){
      v8bf a = *(const v8bf*)&Afr[cur][(wr*2+kh)*512 + lane*8];
      #pragma unroll
      for(int g=0; g<2; ++g){
        v8bf b = *(const v8bf*)&Bfr[cur][((w2*2+g)*2+kh)*512 + lane*8];
        acc[g] = __builtin_amdgcn_mfma_f32_32x32x16_bf16(a, b, acc[g], 0, 0, 0);
      }
    }
    __syncthreads();
  }
  #pragma unroll
  for(int reg=0; reg<16; ++reg){
    int row = r0 + wr*32 + (reg&3) + 8*(reg>>2) + 4*l5;
    int w = row % 25;
    float a0w = asums[w], a1w = asums[25+w], a2w = asums[50+w];
    #pragma unroll
    for(int g=0; g<2; ++g){
      int cc = w2*64 + g*32 + l31;
      float b = a0w*bg0[cc] + a1w*bg0[128+cc] + a2w*bg0[256+cc];
      yb[(size_t)row*128 + cc] = f2bs(fmaxf(acc[g][reg] + b, 0.f));
    }
  }
}

// ---------------------------------------------------------------------------
// kFin<MODE>: sum S partials + bias, LSTM pointwise
// ---------------------------------------------------------------------------
template<int MODE>
__global__ __launch_bounds__(256) void kFin(
    const float* __restrict__ part, const float* __restrict__ c0,
    const float* __restrict__ bias, float* __restrict__ out, int S)
{
  constexpr int ROWS = (MODE==1)?Nn:Bn;
  const int row = blockIdx.x, u = threadIdx.x;
  size_t hoff = hoffOf<MODE>(row);
  int boff = (MODE==1)?((row&1)*1024):0;
  float zg4[4] = { bias[boff+u], bias[boff+256+u], bias[boff+512+u], bias[boff+768+u] };
  for(int s=0;s<S;++s){
    const float* p = part + ((size_t)s*ROWS + row)*1024;
    #pragma unroll
    for(int g=0;g<4;++g) zg4[g] += p[g*256+u];
  }
  float iv=hsig(zg4[0]), fv=hsig(zg4[1]), gv=ftanh(zg4[2]), ov=hsig(zg4[3]);
  float cc = c0[hoff+u];
  float c2 = fv*cc + iv*gv;
  out[hoff+u] = ov*ftanh(c2);
}

extern "C" void kernel_launch(void* const* d_in, const int* in_sizes, int n_in,
                              void* d_out, int out_size, void* d_ws, size_t ws_size,
                              hipStream_t stream)
{
  const float* x   = (const float*)d_in[0];
  const float* h0  = (const float*)d_in[1];
  const float* c0  = (const float*)d_in[2];
  const float* A   = (const float*)d_in[3];
  const float* ei  = (const float*)d_in[4];
  const float* wg0 = (const float*)d_in[5];
  const float* bg0 = (const float*)d_in[6];
  const float* wg1 = (const float*)d_in[7];
  const float* bg1 = (const float*)d_in[8];
  const float* wr1 = (const float*)d_in[9];
  const float* br1 = (const float*)d_in[10];
  const float* kern  = (const float*)d_in[11];
  const float* kernB = (const float*)d_in[12];
  const float* kernW = (const float*)d_in[13];
  const float* rk    = (const float*)d_in[14];
  const float* rkB   = (const float*)d_in[15];
  const float* rkW   = (const float*)d_in[16];
  const float* bias  = (const float*)d_in[17];
  const float* biasB = (const float*)d_in[18];
  const float* biasW = (const float*)d_in[19];
  float* out = (float*)d_out;
  char* wsb  = (char*)d_ws;

  // ws layout (bytes), total 149.7 MB (< 157.3 MB proven):
  //  [0, 52428800)                        featb (bf16, 102400x256)
  //  [52428800, 94158848)                 weights: WbJ|WbB|WbW|Wc2|Wc1 (41.73 MB, exact)
  //  [94158848, 146587648)   dyn region:  graph temps (ycat 39.3MB | yb 13.1MB; xcat overlays)
  //                                       then h0bJ (52.4 MB, joint phase)
  //                                       then part (split-K partials, 50.3 MB)
  //  [146587648, 149733376)               hB (2 MB) | hW (1 MB)
  unsigned short* featb = (unsigned short*)wsb;
  unsigned short* WbJ = (unsigned short*)(wsb + 52428800);
  unsigned short* WbB = WbJ + 524288;
  unsigned short* WbW = WbB + 6815744;
  unsigned short* Wc2 = WbW + 13369344;
  unsigned short* Wc1 = Wc2 + 131072;
  char* dyn = wsb + 94158848;
  unsigned short* ycat = (unsigned short*)dyn;
  unsigned short* xcat = ycat;
  unsigned short* yb   = (unsigned short*)(dyn + 39321600);
  unsigned short* h0bJ = (unsigned short*)dyn;                  // after graph phase
  float* part = (float*)dyn;                                    // after joint
  unsigned short* hB = (unsigned short*)(wsb + 146587648);
  unsigned short* hW = hB + 1048576;

  // weights -> bf16 fragment order
  kConvW<0><<<(524288+255)/256,   256, 0, stream>>>(kern,  rk,  WbJ, 524288);
  kConvW<1><<<(6815744+255)/256,  256, 0, stream>>>(kernB, rkB, WbB, 6815744);
  kConvW<2><<<(13369344+255)/256, 256, 0, stream>>>(kernW, rkW, WbW, 13369344);
  kConvW<3><<<(131072+255)/256,   256, 0, stream>>>(wg1, wr1, Wc2, 131072);
  kConvW<4><<<(24576+255)/256,    256, 0, stream>>>(wg0, nullptr, Wc1, 24576);
  // h -> bf16 (hB/hW independent region; can run now)
  kConvH<1><<<(262144+255)/256, 256, 0, stream>>>(h0, hB, 262144);
  kConvH<2><<<(131072+255)/256, 256, 0, stream>>>(h0, hW, 131072);

  for(int c=0;c<NCH;++c){
    const float* xc = x + (size_t)c*NnC*(Vv*Dd);
    kMix<64,float>          <<<NnC, 192, 0, stream>>>(xc, A, ei, 0, xcat);
    kGC1<<<RCn/64, 256, 0, stream>>>(xcat, Wc1, bg0, A, ei, yb);
    kMix<128,unsigned short><<<NnC, 384, 0, stream>>>(yb, A, ei, 1875, ycat);
    kGC2<<<RCn/64, 256, 0, stream>>>(ycat, yb, Wc2, bg1, br1, A, ei,
                                     featb + (size_t)c*RCn*256);
  }
  // joint h -> bf16 into dyn (graph temps now dead)
  kConvH<0><<<(6553600+255)/256, 256, 0, stream>>>(h0, h0bJ, 6553600);
  // joint: 64-row tile + dbuf + async, ublk-inner grid (6400 blocks)
  kLSTMm<0,64><<<(N3/64)*4, 256, 0, stream>>>(featb, h0bJ, c0, WbJ, bias, out, 512);
  // body: split-K S=3 (KC=2240), 128-row tile, (32*4) x 3
  kLSTMm<1,128><<<dim3((Nn/128)*4,3), 256, 0, stream>>>(featb, hB, nullptr, WbB, nullptr, part, 2240);
  kFin<1><<<Nn, 256, 0, stream>>>(part, c0, biasB, out, 3);
  // whole: split-K S=6 (KC=2176), (16*4) x 6
  kLSTMm<2,128><<<dim3((Bn/128)*4,6), 256, 0, stream>>>(featb, hW, nullptr, WbW, nullptr, part, 2176);
  kFin<2><<<Bn, 256, 0, stream>>>(part, c0, biasW, out, 6);
}